// Round 11
// baseline (1121.083 us; speedup 1.0000x reference)
//
#include <hip/hip_runtime.h>
#include <cstddef>

// Problem constants
#define BB 32
#define NN 128
#define PP 8128

typedef __attribute__((ext_vector_type(8))) short short8;
typedef __attribute__((ext_vector_type(4))) float floatx4;

union U4S8 { uint4 u; short8 s; };
__device__ __forceinline__ short8 as_s8(uint4 v){ U4S8 x; x.u = v; return x.s; }

// ---------- bf16 helpers ----------
__device__ __forceinline__ unsigned pack_bf16(float a, float b){
  union{float f;unsigned u;}xa,xb; xa.f=a; xb.f=b;
  unsigned ua=xa.u, ub=xb.u;
  ua = (ua + 0x7fffu + ((ua>>16)&1u)) >> 16;
  ub = (ub + 0x7fffu + ((ub>>16)&1u)) >> 16;
  return (ua & 0xffffu) | (ub << 16);
}
__device__ __forceinline__ unsigned short bf16_1(float a){
  union{float f;unsigned u;}x; x.f=a;
  return (unsigned short)((x.u + 0x7fffu + ((x.u>>16)&1u)) >> 16);
}
__device__ __forceinline__ float sigf(float x){ return 1.f/(1.f + __expf(-x)); }

// Bijective block remap (kept from R5).
__device__ __forceinline__ void decode_blk(int gid, int& b, int& j, int& half){
  b    = ((gid>>11)&3)*8 + ((gid>>5)&7);
  j    = ((gid>>9)&3)*32 + (gid&31);
  half = (gid>>8)&1;
}

// ---------- weight conversion + round-0 tables ----------
__global__ __launch_bounds__(256,4) void conv_w_kernel(
  const float* __restrict__ Wl_e, const float* __restrict__ Wm_e,
  const float* __restrict__ Wu_e, const float* __restrict__ Wu_m,
  const float* __restrict__ Wr1, const float* __restrict__ Wr2,
  const float* __restrict__ emb,
  unsigned* __restrict__ wT, unsigned* __restrict__ wr1T,
  unsigned* __restrict__ wr2T,
  float* __restrict__ embZ, float* __restrict__ embM, float* __restrict__ embU)
{
  int tid = blockIdx.x*256 + threadIdx.x;   // 65536 total
  if (tid < 2048) {   // Wr2 [256][10] -> B-frag layout [16 cols][128 k2], zero-padded
    int c = tid >> 7, k2 = tid & 127;
    unsigned v = 0;
    if (c < 10) v = pack_bf16(Wr2[(2*k2)*10 + c], Wr2[(2*k2+1)*10 + c]);
    wr2T[c*128 + k2] = v;
  }
  if (tid >= 4096 && tid < 5632) {   // round-0 tables: emb(4x128) @ W(128x128), f32
    int idx = tid - 4096;            // 0..1535
    int tb = idx >> 9;               // 0..2
    int r  = idx & 511;
    int id = r >> 7, c = r & 127;
    const float* W = (tb==0) ? Wl_e : (tb==1) ? Wm_e : Wu_e;
    float s = 0.f;
    #pragma unroll 4
    for (int k = 0; k < 128; ++k) s += emb[id*128 + k] * W[(size_t)k*128 + c];
    float* T = (tb==0) ? embZ : (tb==1) ? embM : embU;
    T[r] = s;
  }
  if (tid < 32768) {
    int mat = tid >> 13, r = tid & 8191;
    int k2 = r >> 7, c = r & 127;
    const float* W = (mat==0) ? Wl_e : (mat==1) ? Wm_e : (mat==2) ? Wu_e : Wu_m;
    wT[mat*8192 + c*64 + k2] = pack_bf16(W[(2*k2)*128 + c], W[(2*k2+1)*128 + c]);
  } else {
    int r = tid - 32768;
    int k2 = r >> 8, c = r & 255;
    wr1T[(size_t)c*128 + k2] = pack_bf16(Wr1[(2*k2)*256 + c], Wr1[(2*k2+1)*256 + c]);
  }
}

// ---------- fused GRU + node projections ----------
__global__ __launch_bounds__(256,4) void gru_proj_kernel(
  int do_gru,
  const float* __restrict__ ms0, const float* __restrict__ ms1,
  const float* __restrict__ h_in, float* __restrict__ h_out,
  const float* __restrict__ W_ih, const float* __restrict__ W_hh,
  const float* __restrict__ b_ih, const float* __restrict__ b_hh,
  const float* __restrict__ Wl_w, const float* __restrict__ Wl_v,
  const float* __restrict__ Wm_w, const float* __restrict__ Wm_v,
  const int* __restrict__ event_nums,
  float* __restrict__ a_l, float* __restrict__ b_l,
  float* __restrict__ a_m, float* __restrict__ b_m)
{
  __shared__ float h_s[4][128];
  __shared__ float ms_s[4][128];
  const int t = threadIdx.x, blk = blockIdx.x;
  const int b = blk >> 5, n0 = (blk & 31) * 4;
  const int vn = event_nums[b];
  const int g = t >> 6, l = t & 63;
  const int row = b*128 + n0 + g;

  h_s[g][l]    = h_in[(size_t)row*128 + l];
  h_s[g][l+64] = h_in[(size_t)row*128 + l + 64];
  if (do_gru) {
    float v0 = ms0[(size_t)row*128 + l];
    float v1 = ms0[(size_t)row*128 + l + 64];
    if (vn > 64) {
      v0 += ms1[(size_t)row*128 + l];
      v1 += ms1[(size_t)row*128 + l + 64];
    }
    ms_s[g][l]    = v0;
    ms_s[g][l+64] = v1;
  }
  __syncthreads();

  if (do_gru) {
    float acc[12] = {};
    #pragma unroll 4
    for (int k = 0; k < 128; ++k) {
      float mv = ms_s[g][k], hv = h_s[g][k];
      #pragma unroll
      for (int u = 0; u < 6; ++u) {
        acc[u]   += mv * W_ih[(size_t)k*384 + l + 64*u];
        acc[6+u] += hv * W_hh[(size_t)k*384 + l + 64*u];
      }
    }
    const bool valid = (n0 + g) < vn;
    float hnew[2];
    #pragma unroll
    for (int u = 0; u < 2; ++u) {
      int c = l + 64*u;
      float ir = acc[u]     + b_ih[c];
      float iz = acc[u+2]   + b_ih[128+c];
      float in_= acc[u+4]   + b_ih[256+c];
      float hr = acc[6+u]   + b_hh[c];
      float hz = acc[8+u]   + b_hh[128+c];
      float hn = acc[10+u]  + b_hh[256+c];
      float r  = sigf(ir + hr);
      float zg = sigf(iz + hz);
      float nn = tanhf(in_ + r*hn);
      float hold = h_s[g][c];
      hnew[u] = valid ? (1.f - zg)*nn + zg*hold : hold;
    }
    __syncthreads();
    #pragma unroll
    for (int u = 0; u < 2; ++u) {
      int c = l + 64*u;
      h_s[g][c] = hnew[u];
      h_out[(size_t)row*128 + c] = hnew[u];
    }
    __syncthreads();
  }

  {
    const float* Wp[4] = {Wl_w, Wl_v, Wm_w, Wm_v};
    float* Op[4] = {a_l, b_l, a_m, b_m};
    float acc2[8] = {};
    #pragma unroll 4
    for (int k = 0; k < 128; ++k) {
      float hv = h_s[g][k];
      #pragma unroll
      for (int u = 0; u < 8; ++u)
        acc2[u] += hv * Wp[u>>1][(size_t)k*128 + l + 64*(u&1)];
    }
    #pragma unroll
    for (int u = 0; u < 8; ++u)
      Op[u>>1][(size_t)row*128 + l + 64*(u&1)] = acc2[u];
  }
}

// ---------- edge round 0: table-driven, per-wave autonomous, ct-outer, 8 blocks/CU ----------
__global__ __launch_bounds__(256,8) void edge_round_first(
  unsigned* __restrict__ eg,
  const unsigned* __restrict__ wT,
  const int* __restrict__ ids,
  const float* __restrict__ embZ, const float* __restrict__ embM,
  const float* __restrict__ embU,
  const float* __restrict__ a_l, const float* __restrict__ b_l,
  const float* __restrict__ a_m, const float* __restrict__ b_m,
  const float* __restrict__ bl1, const float* __restrict__ wl2,
  const float* __restrict__ bl2, const float* __restrict__ bm,
  const float* __restrict__ bu,
  const int* __restrict__ event_nums,
  float* __restrict__ ms0, float* __restrict__ ms1)
{
  __shared__ unsigned m_a[64*68];
  __shared__ float msum4[4][128];
  unsigned short* m16 = (unsigned short*)m_a;

  const int t = threadIdx.x;
  int b, j, half;
  decode_blk(blockIdx.x, b, j, half);
  const int vn = event_nums[b];
  const int row0 = half*64;
  int vnl = vn - row0; vnl = vnl < 0 ? 0 : (vnl > 64 ? 64 : vnl);
  if (j >= vn || vnl == 0) return;

  const int lane = t & 63, wv = t >> 6;
  const int q = lane >> 4, n = lane & 15;
  const int wrow = wv*16;

  msum4[wv][lane] = 0.f;
  msum4[wv][lane + 64] = 0.f;

  unsigned* eblk = eg + (size_t)(b*128 + j) * 8192;
  const float bl2v = bl2[0];
  const unsigned* wum = wT + 24576;
  const float* bLrow = b_l + (size_t)(b*128 + j)*128;
  const float* bMrow = b_m + (size_t)(b*128 + j)*128;

  if (vnl > wrow) {
    int idv[4];
    #pragma unroll
    for (int r = 0; r < 4; ++r)
      idv[r] = ids[((size_t)(b*128 + row0 + wrow + q*4 + r))*128 + j];

    const float* aLb = a_l + (size_t)(b*128 + row0)*128;
    const float* aMb = a_m + (size_t)(b*128 + row0)*128;

    // ---- Z from tables, ct-outer -> in-register sigmoid ----
    float szr[4] = {0.f,0.f,0.f,0.f};
    #pragma unroll
    for (int ct = 0; ct < 8; ++ct) {
      int c = ct*16 + n;
      float wl2v = wl2[c];
      float bLv  = bLrow[c] + bl1[c];
      #pragma unroll
      for (int r = 0; r < 4; ++r) {
        int lrow = wrow + q*4 + r;
        float zv = fmaxf(embZ[idv[r]*128 + c] + aLb[(size_t)lrow*128 + c] + bLv, 0.f);
        szr[r] += zv * wl2v;
      }
    }
    #pragma unroll
    for (int r = 0; r < 4; ++r) {
      szr[r] += __shfl_xor(szr[r], 1);
      szr[r] += __shfl_xor(szr[r], 2);
      szr[r] += __shfl_xor(szr[r], 4);
      szr[r] += __shfl_xor(szr[r], 8);
    }
    float sc[4];
    #pragma unroll
    for (int r = 0; r < 4; ++r) {
      int lrow = wrow + q*4 + r;
      sc[r] = (lrow < vnl) ? sigf(szr[r] + bl2v) : 0.f;
    }

    // ---- M from tables, ct-outer -> m16 + per-wave msum ----
    #pragma unroll
    for (int ct = 0; ct < 8; ++ct) {
      int c = ct*16 + n;
      float bMv = bMrow[c] + bm[c];
      float colsum = 0.f;
      #pragma unroll
      for (int r = 0; r < 4; ++r) {
        int lrow = wrow + q*4 + r;
        float mv = fmaxf(embM[idv[r]*128 + c] + aMb[(size_t)lrow*128 + c] + bMv, 0.f) * sc[r];
        m16[lrow*136 + c] = bf16_1(mv);
        colsum += mv;
      }
      colsum += __shfl_xor(colsum, 16);
      colsum += __shfl_xor(colsum, 32);
      if (lane < 16) msum4[wv][c] = colsum;
    }

    // ---- hoist M A-fragments (own rows) to registers, then U ct-outer ----
    uint4 mA[4];
    #pragma unroll
    for (int kb = 0; kb < 4; ++kb)
      mA[kb] = *(const uint4*)&m_a[(wrow + n)*68 + kb*16 + q*4];

    #pragma unroll
    for (int ct = 0; ct < 8; ++ct) {
      int c = ct*16 + n;
      floatx4 au;
      #pragma unroll
      for (int r = 0; r < 4; ++r) au[r] = embU[idv[r]*128 + c];
      #pragma unroll
      for (int kb = 0; kb < 4; ++kb) {
        uint4 bb = *(const uint4*)(wum + c*64 + kb*16 + q*4);
        au = __builtin_amdgcn_mfma_f32_16x16x32_bf16(as_s8(mA[kb]), as_s8(bb), au, 0, 0, 0);
      }
      float buv = bu[c];
      #pragma unroll
      for (int r = 0; r < 4; ++r) {
        int lrow = wrow + q*4 + r;
        m16[lrow*136 + c] = bf16_1(fmaxf(au[r] + buv, 0.f));
      }
    }

    // per-wave writeback of own 16 rows
    #pragma unroll
    for (int it = 0; it < 4; ++it) {
      int lr = wrow + it*4 + q;
      int c4 = n*4;
      if (row0 + lr < vn)
        *(uint4*)&eblk[(size_t)(row0 + lr)*64 + c4] = *(const uint4*)&m_a[lr*68 + c4];
    }
  }

  __syncthreads();   // only barrier: msum slices final
  if (t < 128) {
    float* msH = half ? ms1 : ms0;
    msH[(size_t)(b*128 + j)*128 + t] =
      msum4[0][t] + msum4[1][t] + msum4[2][t] + msum4[3][t];
  }
}

// ---------- edge rounds >=1: per-wave autonomous, ct-outer, 8 blocks/CU ----------
// 40 VGPR + 4 AGPR body (R9-verified) fits the <=64-reg tier: 8 waves/SIMD.
// LDS 19456 B x 8 blocks = 155.6 KB <= 160 KB.
__global__ __launch_bounds__(256,8) void edge_round_rest(
  unsigned* __restrict__ eg,
  const unsigned* __restrict__ wT,
  const float* __restrict__ a_l, const float* __restrict__ b_l,
  const float* __restrict__ a_m, const float* __restrict__ b_m,
  const float* __restrict__ bl1, const float* __restrict__ wl2,
  const float* __restrict__ bl2, const float* __restrict__ bm,
  const float* __restrict__ bu,
  const int* __restrict__ event_nums,
  float* __restrict__ ms0, float* __restrict__ ms1)
{
  __shared__ unsigned m_a[64*68];
  __shared__ float msum4[4][128];
  unsigned short* m16 = (unsigned short*)m_a;

  const int t = threadIdx.x;
  int b, j, half;
  decode_blk(blockIdx.x, b, j, half);
  const int vn = event_nums[b];
  const int row0 = half*64;
  int vnl = vn - row0; vnl = vnl < 0 ? 0 : (vnl > 64 ? 64 : vnl);
  if (j >= vn || vnl == 0) return;

  const int lane = t & 63, wv = t >> 6;
  const int q = lane >> 4, n = lane & 15;
  const int wrow = wv*16;

  msum4[wv][lane] = 0.f;
  msum4[wv][lane + 64] = 0.f;

  unsigned* eblk = eg + (size_t)(b*128 + j) * 8192;
  const float bl2v = bl2[0];

  const unsigned* wz  = wT;
  const unsigned* wm  = wT + 8192;
  const unsigned* wue = wT + 16384;
  const unsigned* wum = wT + 24576;
  const float* bLrow = b_l + (size_t)(b*128 + j)*128;
  const float* bMrow = b_m + (size_t)(b*128 + j)*128;

  if (vnl > wrow) {
    // E-tile A-fragments for this wave's 16 rows (rows >= vn garbage; masked below)
    uint4 eA[4];
    #pragma unroll
    for (int kb = 0; kb < 4; ++kb)
      eA[kb] = *(const uint4*)&eblk[(size_t)(row0 + wrow + n)*64 + kb*16 + q*4];

    const float* aLb = a_l + (size_t)(b*128 + row0)*128;
    const float* aMb = a_m + (size_t)(b*128 + row0)*128;

    // ---- PASS Z: ct-outer, single accumulator ----
    float szr[4] = {0.f,0.f,0.f,0.f};
    #pragma unroll
    for (int ct = 0; ct < 8; ++ct) {
      int c = ct*16 + n;
      floatx4 az = (floatx4){0.f,0.f,0.f,0.f};
      #pragma unroll
      for (int kb = 0; kb < 4; ++kb) {
        uint4 bb = *(const uint4*)(wz + c*64 + kb*16 + q*4);
        az = __builtin_amdgcn_mfma_f32_16x16x32_bf16(as_s8(eA[kb]), as_s8(bb), az, 0, 0, 0);
      }
      float wl2v = wl2[c];
      float bLv  = bLrow[c] + bl1[c];
      #pragma unroll
      for (int r = 0; r < 4; ++r) {
        int lrow = wrow + q*4 + r;
        float zv = fmaxf(az[r] + aLb[(size_t)lrow*128 + c] + bLv, 0.f);
        szr[r] += zv * wl2v;
      }
    }
    #pragma unroll
    for (int r = 0; r < 4; ++r) {
      szr[r] += __shfl_xor(szr[r], 1);
      szr[r] += __shfl_xor(szr[r], 2);
      szr[r] += __shfl_xor(szr[r], 4);
      szr[r] += __shfl_xor(szr[r], 8);
    }
    float sc[4];
    #pragma unroll
    for (int r = 0; r < 4; ++r) {
      int lrow = wrow + q*4 + r;
      sc[r] = (lrow < vnl) ? sigf(szr[r] + bl2v) : 0.f;
    }

    // ---- PASS M: ct-outer ----
    #pragma unroll
    for (int ct = 0; ct < 8; ++ct) {
      int c = ct*16 + n;
      floatx4 am = (floatx4){0.f,0.f,0.f,0.f};
      #pragma unroll
      for (int kb = 0; kb < 4; ++kb) {
        uint4 bb = *(const uint4*)(wm + c*64 + kb*16 + q*4);
        am = __builtin_amdgcn_mfma_f32_16x16x32_bf16(as_s8(eA[kb]), as_s8(bb), am, 0, 0, 0);
      }
      float bMv = bMrow[c] + bm[c];
      float colsum = 0.f;
      #pragma unroll
      for (int r = 0; r < 4; ++r) {
        int lrow = wrow + q*4 + r;
        float mv = fmaxf(am[r] + aMb[(size_t)lrow*128 + c] + bMv, 0.f) * sc[r];
        m16[lrow*136 + c] = bf16_1(mv);
        colsum += mv;
      }
      colsum += __shfl_xor(colsum, 16);
      colsum += __shfl_xor(colsum, 32);
      if (lane < 16) msum4[wv][c] = colsum;
    }

    // ---- hoist M A-fragments before any U write (removes overwrite hazard) ----
    uint4 mA[4];
    #pragma unroll
    for (int kb = 0; kb < 4; ++kb)
      mA[kb] = *(const uint4*)&m_a[(wrow + n)*68 + kb*16 + q*4];

    // ---- PASS U: ct-outer (E@Wu_e from eA + M@Wu_m from mA) ----
    #pragma unroll
    for (int ct = 0; ct < 8; ++ct) {
      int c = ct*16 + n;
      floatx4 au = (floatx4){0.f,0.f,0.f,0.f};
      #pragma unroll
      for (int kb = 0; kb < 4; ++kb) {
        uint4 bb = *(const uint4*)(wue + c*64 + kb*16 + q*4);
        au = __builtin_amdgcn_mfma_f32_16x16x32_bf16(as_s8(eA[kb]), as_s8(bb), au, 0, 0, 0);
      }
      #pragma unroll
      for (int kb = 0; kb < 4; ++kb) {
        uint4 bb = *(const uint4*)(wum + c*64 + kb*16 + q*4);
        au = __builtin_amdgcn_mfma_f32_16x16x32_bf16(as_s8(mA[kb]), as_s8(bb), au, 0, 0, 0);
      }
      float buv = bu[c];
      #pragma unroll
      for (int r = 0; r < 4; ++r) {
        int lrow = wrow + q*4 + r;
        m16[lrow*136 + c] = bf16_1(fmaxf(au[r] + buv, 0.f));
      }
    }

    // per-wave writeback of own 16 rows
    #pragma unroll
    for (int it = 0; it < 4; ++it) {
      int lr = wrow + it*4 + q;
      int c4 = n*4;
      if (row0 + lr < vn)
        *(uint4*)&eblk[(size_t)(row0 + lr)*64 + c4] = *(const uint4*)&m_a[lr*68 + c4];
    }
  }

  __syncthreads();   // only barrier: msum slices final
  if (t < 128) {
    float* msH = half ? ms1 : ms0;
    msH[(size_t)(b*128 + j)*128 + t] =
      msum4[0][t] + msum4[1][t] + msum4[2][t] + msum4[3][t];
  }
}

// ---------- MFMA readout, both GEMMs on matrix cores ----------
__global__ __launch_bounds__(256,4) void readout_mfma(
  const unsigned* __restrict__ eg,
  const unsigned* __restrict__ wr1T,
  const unsigned* __restrict__ wr2T,
  const float* __restrict__ br1, const float* __restrict__ br2,
  const int* __restrict__ event_nums, float* __restrict__ out)
{
  __shared__ unsigned f_s[64*132];
  __shared__ int iu_s[64], ju_s[64];
  unsigned short* h16 = (unsigned short*)f_s;

  const int t = threadIdx.x;
  const int b = blockIdx.x / 127, pb = blockIdx.x % 127;
  const int vn = event_nums[b];

  if (t < 64) {
    int p = pb*64 + t;
    float disc = (float)((2*NN-1)*(2*NN-1) - 8*p);
    int iu = (int)(((float)(2*NN-1) - sqrtf(disc)) * 0.5f);
    if (iu < 0) iu = 0; if (iu > NN-2) iu = NN-2;
    while (iu < NN-2 && ((iu+1)*(2*NN-2-iu))/2 <= p) ++iu;
    while (iu > 0 && (iu*(2*NN-1-iu))/2 > p) --iu;
    int ju = p - (iu*(2*NN-1-iu))/2 + iu + 1;
    iu_s[t] = iu; ju_s[t] = ju;
  }
  __syncthreads();

  #pragma unroll
  for (int it = 0; it < 8; ++it) {
    int f4 = it*1024 + t*4;
    int pr = f4 >> 7, w = f4 & 127;
    int side = w >> 6, k2 = w & 63;
    int iu = iu_s[pr], ju = ju_s[pr];
    size_t base = side ? (((size_t)(b*128 + iu))*128 + ju)*64
                       : (((size_t)(b*128 + ju))*128 + iu)*64;
    *(uint4*)&f_s[pr*132 + w] = *(const uint4*)&eg[base + k2];
  }
  __syncthreads();

  const int lane = t & 63, wv = t >> 6;
  const int q = lane >> 4, n = lane & 15;
  int colg[4];
  #pragma unroll
  for (int ct = 0; ct < 4; ++ct) colg[ct] = wv*64 + ct*16 + n;

  floatx4 acc[4][4];
  #pragma unroll
  for (int rt = 0; rt < 4; ++rt)
    #pragma unroll
    for (int ct = 0; ct < 4; ++ct) acc[rt][ct] = (floatx4){0.f,0.f,0.f,0.f};

  #pragma unroll
  for (int kb = 0; kb < 8; ++kb) {
    uint4 bb[4];
    #pragma unroll
    for (int ct = 0; ct < 4; ++ct) bb[ct] = *(const uint4*)(wr1T + (size_t)colg[ct]*128 + kb*16 + q*4);
    #pragma unroll
    for (int rt = 0; rt < 4; ++rt) {
      uint4 a = *(const uint4*)&f_s[(rt*16 + n)*132 + kb*16 + q*4];
      #pragma unroll
      for (int ct = 0; ct < 4; ++ct)
        acc[rt][ct] = __builtin_amdgcn_mfma_f32_16x16x32_bf16(as_s8(a), as_s8(bb[ct]), acc[rt][ct], 0, 0, 0);
    }
  }
  __syncthreads();

  {
    float brv[4];
    #pragma unroll
    for (int ct = 0; ct < 4; ++ct) brv[ct] = br1[colg[ct]];
    #pragma unroll
    for (int rt = 0; rt < 4; ++rt)
      #pragma unroll
      for (int ct = 0; ct < 4; ++ct)
        #pragma unroll
        for (int r = 0; r < 4; ++r) {
          int pr = rt*16 + q*4 + r;
          h16[pr*264 + colg[ct]] = bf16_1(fmaxf(acc[rt][ct][r] + brv[ct], 0.f));
        }
  }
  __syncthreads();

  floatx4 acc2 = (floatx4){0.f,0.f,0.f,0.f};
  #pragma unroll
  for (int kb = 0; kb < 8; ++kb) {
    uint4 bb = *(const uint4*)(wr2T + n*128 + kb*16 + q*4);
    uint4 a  = *(const uint4*)&f_s[(wv*16 + n)*132 + kb*16 + q*4];
    acc2 = __builtin_amdgcn_mfma_f32_16x16x32_bf16(as_s8(a), as_s8(bb), acc2, 0, 0, 0);
  }

  if (n < 10) {
    float bias = br2[n];
    #pragma unroll
    for (int r = 0; r < 4; ++r) {
      int pr = wv*16 + q*4 + r;
      int iu = iu_s[pr], ju = ju_s[pr];
      if (ju < vn) {
        int idx = iu*vn - (iu*(iu+1))/2 + (ju - iu - 1);
        out[(((size_t)b*5 + (n>>1))*PP + idx)*2 + (n&1)] = acc2[r] + bias;
      }
    }
  }
}

extern "C" void kernel_launch(void* const* d_in, const int* in_sizes, int n_in,
                              void* d_out, int out_size, void* d_ws, size_t ws_size,
                              hipStream_t stream) {
  const int*   edge_ids      = (const int*)d_in[0];
  const float* node_features = (const float*)d_in[1];
  const int*   event_nums    = (const int*)d_in[3];
  const float* emb  = (const float*)d_in[4];
  const float* Wl_e = (const float*)d_in[5];
  const float* Wl_w = (const float*)d_in[6];
  const float* Wl_v = (const float*)d_in[7];
  const float* bl1  = (const float*)d_in[8];
  const float* wl2  = (const float*)d_in[9];
  const float* bl2  = (const float*)d_in[10];
  const float* Wm_w = (const float*)d_in[11];
  const float* Wm_v = (const float*)d_in[12];
  const float* Wm_e = (const float*)d_in[13];
  const float* bm   = (const float*)d_in[14];
  const float* Wu_e = (const float*)d_in[15];
  const float* Wu_m = (const float*)d_in[16];
  const float* bu   = (const float*)d_in[17];
  const float* W_ih = (const float*)d_in[18];
  const float* W_hh = (const float*)d_in[19];
  const float* b_ih = (const float*)d_in[20];
  const float* b_hh = (const float*)d_in[21];
  const float* Wr1  = (const float*)d_in[22];
  const float* br1  = (const float*)d_in[23];
  const float* Wr2  = (const float*)d_in[24];
  const float* br2  = (const float*)d_in[25];

  const size_t SZ_E = (size_t)134217728;       // B*N*N*64 u32
  const size_t SZ_S = (size_t)2097152;         // B*N*128 f32
  const size_t SZ_W = (size_t)131072;          // 32768 u32
  const size_t SZ_W2 = (size_t)8192;           // 2048 u32
  const size_t SZ_TAB = (size_t)2048;          // 512 f32 each
  const size_t need = SZ_E + 7*SZ_S + 2*SZ_W + SZ_W2 + 3*SZ_TAB;

  hipMemsetAsync(d_out, 0, (size_t)out_size * sizeof(float), stream);
  if (ws_size < need) return;

  char* w = (char*)d_ws;
  unsigned* eg   = (unsigned*)w; w += SZ_E;
  float* h_ws = (float*)w; w += SZ_S;
  float* a_l  = (float*)w; w += SZ_S;
  float* b_l  = (float*)w; w += SZ_S;
  float* a_m  = (float*)w; w += SZ_S;
  float* b_m  = (float*)w; w += SZ_S;
  float* ms0  = (float*)w; w += SZ_S;
  float* ms1  = (float*)w; w += SZ_S;
  unsigned* wT   = (unsigned*)w; w += SZ_W;
  unsigned* wr1T = (unsigned*)w; w += SZ_W;
  unsigned* wr2T = (unsigned*)w; w += SZ_W2;
  float* embZ = (float*)w; w += SZ_TAB;
  float* embM = (float*)w; w += SZ_TAB;
  float* embU = (float*)w; w += SZ_TAB;

  hipLaunchKernelGGL(conv_w_kernel, dim3(256), dim3(256), 0, stream,
      Wl_e, Wm_e, Wu_e, Wu_m, Wr1, Wr2, emb, wT, wr1T, wr2T, embZ, embM, embU);

  hipLaunchKernelGGL(gru_proj_kernel, dim3(1024), dim3(256), 0, stream,
      0, ms0, ms1, node_features, h_ws, W_ih, W_hh, b_ih, b_hh,
      Wl_w, Wl_v, Wm_w, Wm_v, event_nums, a_l, b_l, a_m, b_m);

  for (int r = 0; r < 3; ++r) {
    if (r == 0) {
      hipLaunchKernelGGL(edge_round_first, dim3(8192), dim3(256), 0, stream,
          eg, wT, edge_ids, embZ, embM, embU,
          a_l, b_l, a_m, b_m, bl1, wl2, bl2, bm, bu, event_nums, ms0, ms1);
    } else {
      hipLaunchKernelGGL(edge_round_rest, dim3(8192), dim3(256), 0, stream,
          eg, wT, a_l, b_l, a_m, b_m, bl1, wl2, bl2, bm, bu, event_nums, ms0, ms1);
    }
    if (r < 2) {
      const float* hin = (r == 0) ? node_features : h_ws;
      hipLaunchKernelGGL(gru_proj_kernel, dim3(1024), dim3(256), 0, stream,
          1, ms0, ms1, hin, h_ws, W_ih, W_hh, b_ih, b_hh,
          Wl_w, Wl_v, Wm_w, Wm_v, event_nums, a_l, b_l, a_m, b_m);
    }
  }

  hipLaunchKernelGGL(readout_mfma, dim3(BB*127), dim3(256), 0, stream,
      eg, wr1T, wr2T, br1, br2, event_nums, (float*)d_out);
}

// Round 12
// 759.903 us; speedup vs baseline: 1.4753x; 1.4753x over previous
//
#include <hip/hip_runtime.h>
#include <cstddef>

// Problem constants
#define BB 32
#define NN 128
#define PP 8128

typedef __attribute__((ext_vector_type(8))) short short8;
typedef __attribute__((ext_vector_type(4))) float floatx4;

union U4S8 { uint4 u; short8 s; };
__device__ __forceinline__ short8 as_s8(uint4 v){ U4S8 x; x.u = v; return x.s; }

// ---------- bf16 helpers ----------
__device__ __forceinline__ unsigned pack_bf16(float a, float b){
  union{float f;unsigned u;}xa,xb; xa.f=a; xb.f=b;
  unsigned ua=xa.u, ub=xb.u;
  ua = (ua + 0x7fffu + ((ua>>16)&1u)) >> 16;
  ub = (ub + 0x7fffu + ((ub>>16)&1u)) >> 16;
  return (ua & 0xffffu) | (ub << 16);
}
__device__ __forceinline__ unsigned short bf16_1(float a){
  union{float f;unsigned u;}x; x.f=a;
  return (unsigned short)((x.u + 0x7fffu + ((x.u>>16)&1u)) >> 16);
}
__device__ __forceinline__ float sigf(float x){ return 1.f/(1.f + __expf(-x)); }

// Bijective block remap. CU residue class = gid mod 256 (varying bits are 12..8).
// b <- {12,11 | 7,6,5}, j <- {10,9 | 4..0}, half <- {8}: every residue class spans
// 4 b's x 4 j-strata x 2 halves -> no pinned dimension.
__device__ __forceinline__ void decode_blk(int gid, int& b, int& j, int& half){
  b    = ((gid>>11)&3)*8 + ((gid>>5)&7);
  j    = ((gid>>9)&3)*32 + (gid&31);
  half = (gid>>8)&1;
}

// ---------- weight conversion + round-0 tables ----------
__global__ __launch_bounds__(256,4) void conv_w_kernel(
  const float* __restrict__ Wl_e, const float* __restrict__ Wm_e,
  const float* __restrict__ Wu_e, const float* __restrict__ Wu_m,
  const float* __restrict__ Wr1, const float* __restrict__ Wr2,
  const float* __restrict__ emb,
  unsigned* __restrict__ wT, unsigned* __restrict__ wr1T,
  unsigned* __restrict__ wr2T,
  float* __restrict__ embZ, float* __restrict__ embM, float* __restrict__ embU)
{
  int tid = blockIdx.x*256 + threadIdx.x;   // 65536 total
  if (tid < 2048) {   // Wr2 [256][10] -> B-frag layout [16 cols][128 k2], zero-padded
    int c = tid >> 7, k2 = tid & 127;
    unsigned v = 0;
    if (c < 10) v = pack_bf16(Wr2[(2*k2)*10 + c], Wr2[(2*k2+1)*10 + c]);
    wr2T[c*128 + k2] = v;
  }
  if (tid >= 4096 && tid < 5632) {   // round-0 tables: emb(4x128) @ W(128x128), f32
    int idx = tid - 4096;            // 0..1535
    int tb = idx >> 9;               // 0..2
    int r  = idx & 511;
    int id = r >> 7, c = r & 127;
    const float* W = (tb==0) ? Wl_e : (tb==1) ? Wm_e : Wu_e;
    float s = 0.f;
    #pragma unroll 4
    for (int k = 0; k < 128; ++k) s += emb[id*128 + k] * W[(size_t)k*128 + c];
    float* T = (tb==0) ? embZ : (tb==1) ? embM : embU;
    T[r] = s;
  }
  if (tid < 32768) {
    int mat = tid >> 13, r = tid & 8191;
    int k2 = r >> 7, c = r & 127;
    const float* W = (mat==0) ? Wl_e : (mat==1) ? Wm_e : (mat==2) ? Wu_e : Wu_m;
    wT[mat*8192 + c*64 + k2] = pack_bf16(W[(2*k2)*128 + c], W[(2*k2+1)*128 + c]);
  } else {
    int r = tid - 32768;
    int k2 = r >> 8, c = r & 255;
    wr1T[(size_t)c*128 + k2] = pack_bf16(Wr1[(2*k2)*256 + c], Wr1[(2*k2+1)*256 + c]);
  }
}

// ---------- fused GRU + node projections ----------
__global__ __launch_bounds__(256,4) void gru_proj_kernel(
  int do_gru,
  const float* __restrict__ ms0, const float* __restrict__ ms1,
  const float* __restrict__ h_in, float* __restrict__ h_out,
  const float* __restrict__ W_ih, const float* __restrict__ W_hh,
  const float* __restrict__ b_ih, const float* __restrict__ b_hh,
  const float* __restrict__ Wl_w, const float* __restrict__ Wl_v,
  const float* __restrict__ Wm_w, const float* __restrict__ Wm_v,
  const int* __restrict__ event_nums,
  float* __restrict__ a_l, float* __restrict__ b_l,
  float* __restrict__ a_m, float* __restrict__ b_m)
{
  __shared__ float h_s[4][128];
  __shared__ float ms_s[4][128];
  const int t = threadIdx.x, blk = blockIdx.x;
  const int b = blk >> 5, n0 = (blk & 31) * 4;
  const int vn = event_nums[b];
  const int g = t >> 6, l = t & 63;
  const int row = b*128 + n0 + g;

  h_s[g][l]    = h_in[(size_t)row*128 + l];
  h_s[g][l+64] = h_in[(size_t)row*128 + l + 64];
  if (do_gru) {
    float v0 = ms0[(size_t)row*128 + l];
    float v1 = ms0[(size_t)row*128 + l + 64];
    if (vn > 64) {
      v0 += ms1[(size_t)row*128 + l];
      v1 += ms1[(size_t)row*128 + l + 64];
    }
    ms_s[g][l]    = v0;
    ms_s[g][l+64] = v1;
  }
  __syncthreads();

  if (do_gru) {
    float acc[12] = {};
    #pragma unroll 4
    for (int k = 0; k < 128; ++k) {
      float mv = ms_s[g][k], hv = h_s[g][k];
      #pragma unroll
      for (int u = 0; u < 6; ++u) {
        acc[u]   += mv * W_ih[(size_t)k*384 + l + 64*u];
        acc[6+u] += hv * W_hh[(size_t)k*384 + l + 64*u];
      }
    }
    const bool valid = (n0 + g) < vn;
    float hnew[2];
    #pragma unroll
    for (int u = 0; u < 2; ++u) {
      int c = l + 64*u;
      float ir = acc[u]     + b_ih[c];
      float iz = acc[u+2]   + b_ih[128+c];
      float in_= acc[u+4]   + b_ih[256+c];
      float hr = acc[6+u]   + b_hh[c];
      float hz = acc[8+u]   + b_hh[128+c];
      float hn = acc[10+u]  + b_hh[256+c];
      float r  = sigf(ir + hr);
      float zg = sigf(iz + hz);
      float nn = tanhf(in_ + r*hn);
      float hold = h_s[g][c];
      hnew[u] = valid ? (1.f - zg)*nn + zg*hold : hold;
    }
    __syncthreads();
    #pragma unroll
    for (int u = 0; u < 2; ++u) {
      int c = l + 64*u;
      h_s[g][c] = hnew[u];
      h_out[(size_t)row*128 + c] = hnew[u];
    }
    __syncthreads();
  }

  {
    const float* Wp[4] = {Wl_w, Wl_v, Wm_w, Wm_v};
    float* Op[4] = {a_l, b_l, a_m, b_m};
    float acc2[8] = {};
    #pragma unroll 4
    for (int k = 0; k < 128; ++k) {
      float hv = h_s[g][k];
      #pragma unroll
      for (int u = 0; u < 8; ++u)
        acc2[u] += hv * Wp[u>>1][(size_t)k*128 + l + 64*(u&1)];
    }
    #pragma unroll
    for (int u = 0; u < 8; ++u)
      Op[u>>1][(size_t)row*128 + l + 64*(u&1)] = acc2[u];
  }
}

// ---------- edge round 0: table-driven (no E GEMMs), only M@Wu_m on MFMA ----------
__global__ __launch_bounds__(256,4) void edge_round_first(
  unsigned* __restrict__ eg,
  const unsigned* __restrict__ wT,     // need wum = wT+24576
  const int* __restrict__ ids,
  const float* __restrict__ embZ, const float* __restrict__ embM,
  const float* __restrict__ embU,
  const float* __restrict__ a_l, const float* __restrict__ b_l,
  const float* __restrict__ a_m, const float* __restrict__ b_m,
  const float* __restrict__ bl1, const float* __restrict__ wl2,
  const float* __restrict__ bl2, const float* __restrict__ bm,
  const float* __restrict__ bu,
  const int* __restrict__ event_nums,
  float* __restrict__ ms0, float* __restrict__ ms1)
{
  __shared__ unsigned m_a[64*68];
  __shared__ float adj[64], msum[128];
  __shared__ float bL_s[128], bM_s[128], bu_s[128], wl2_s[128];
  __shared__ float tabZ[512], tabM[512], tabU[512];
  __shared__ int id_s[64];
  unsigned short* m16 = (unsigned short*)m_a;

  const int t = threadIdx.x;
  int b, j, half;
  decode_blk(blockIdx.x, b, j, half);
  const int vn = event_nums[b];
  const int row0 = half*64;
  int vnl = vn - row0; vnl = vnl < 0 ? 0 : (vnl > 64 ? 64 : vnl);
  if (j >= vn || vnl == 0) return;

  unsigned* eblk = eg + (size_t)(b*128 + j) * 8192;
  const float bl2v = bl2[0];

  if (t < 128) {
    bL_s[t] = b_l[(size_t)(b*128 + j)*128 + t] + bl1[t];
    bM_s[t] = b_m[(size_t)(b*128 + j)*128 + t] + bm[t];
    bu_s[t] = bu[t];
    wl2_s[t] = wl2[t];
    msum[t] = 0.f;
  }
  if (t < 64) {
    adj[t] = 0.f;
    id_s[t] = ids[((size_t)(b*128 + row0 + t))*128 + j];
  }
  for (int i = t; i < 512; i += 256) {
    tabZ[i] = embZ[i]; tabM[i] = embM[i]; tabU[i] = embU[i];
  }

  const int lane = t & 63, wv = t >> 6;
  const int q = lane >> 4, n = lane & 15;
  const int rh2 = wv >> 1, ch = wv & 1;

  int nvt = (vnl - rh2*32 + 15) >> 4;
  nvt = nvt < 0 ? 0 : (nvt > 2 ? 2 : nvt);

  const unsigned* wum = wT + 24576;
  int colg[4];
  #pragma unroll
  for (int ct = 0; ct < 4; ++ct) colg[ct] = ch*64 + ct*16 + n;
  int arowi[2];
  #pragma unroll
  for (int rt = 0; rt < 2; ++rt) arowi[rt] = rh2*32 + rt*16 + n;

  // Prefetch a_l / a_m into registers (hide L2/L3 latency under barrier + tables)
  const float* aLb = a_l + (size_t)(b*128 + row0)*128;
  const float* aMb = a_m + (size_t)(b*128 + row0)*128;
  float alv[2][4][4], amv[2][4][4];
  #pragma unroll
  for (int rt = 0; rt < 2; ++rt)
    if (rt < nvt)
      #pragma unroll
      for (int ct = 0; ct < 4; ++ct)
        #pragma unroll
        for (int r = 0; r < 4; ++r) {
          int lrow = rh2*32 + rt*16 + q*4 + r;
          alv[rt][ct][r] = aLb[(size_t)lrow*128 + colg[ct]];
          amv[rt][ct][r] = aMb[(size_t)lrow*128 + colg[ct]];
        }
  __syncthreads();   // B1

  // Z epilogue from tables
  {
    float wl2v[4], bLv[4];
    #pragma unroll
    for (int ct = 0; ct < 4; ++ct) { wl2v[ct] = wl2_s[colg[ct]]; bLv[ct] = bL_s[colg[ct]]; }
    #pragma unroll
    for (int rt = 0; rt < 2; ++rt) {
      if (rt < nvt) {
        float szr[4] = {0.f,0.f,0.f,0.f};
        #pragma unroll
        for (int ct = 0; ct < 4; ++ct) {
          #pragma unroll
          for (int r = 0; r < 4; ++r) {
            int lrow = rh2*32 + rt*16 + q*4 + r;
            float zv = fmaxf(tabZ[id_s[lrow]*128 + colg[ct]] + alv[rt][ct][r] + bLv[ct], 0.f);
            szr[r] += zv * wl2v[ct];
          }
        }
        #pragma unroll
        for (int r = 0; r < 4; ++r) {
          szr[r] += __shfl_xor(szr[r], 1);
          szr[r] += __shfl_xor(szr[r], 2);
          szr[r] += __shfl_xor(szr[r], 4);
          szr[r] += __shfl_xor(szr[r], 8);
        }
        if (n == 0) {
          #pragma unroll
          for (int r = 0; r < 4; ++r)
            atomicAdd(&adj[rh2*32 + rt*16 + q*4 + r], szr[r]);
        }
      }
    }
  }
  __syncthreads();   // B2: adj final

  // M epilogue from tables -> m16, msum (per-thread sigmoid, no svec)
  {
    float bMv[4];
    #pragma unroll
    for (int ct = 0; ct < 4; ++ct) bMv[ct] = bM_s[colg[ct]];
    float colsum[4] = {0.f,0.f,0.f,0.f};
    #pragma unroll
    for (int rt = 0; rt < 2; ++rt) {
      if (rt < nvt) {
        #pragma unroll
        for (int r = 0; r < 4; ++r) {
          int lrow = rh2*32 + rt*16 + q*4 + r;
          float sc = (lrow < vnl) ? sigf(adj[lrow] + bl2v) : 0.f;
          #pragma unroll
          for (int ct = 0; ct < 4; ++ct) {
            float mv = fmaxf(tabM[id_s[lrow]*128 + colg[ct]] + amv[rt][ct][r] + bMv[ct], 0.f) * sc;
            m16[lrow*136 + colg[ct]] = bf16_1(mv);
            colsum[ct] += mv;
          }
        }
      }
    }
    #pragma unroll
    for (int ct = 0; ct < 4; ++ct) {
      float v = colsum[ct];
      v += __shfl_xor(v, 16);
      v += __shfl_xor(v, 32);
      if (lane < 16) atomicAdd(&msum[colg[ct]], v);
    }
  }
  __syncthreads();   // B3
  {
    float* msH = half ? ms1 : ms0;
    if (t < 128) msH[(size_t)(b*128 + j)*128 + t] = msum[t];   // exclusive owner
  }

  // U = tabU gather + M@Wu_m
  floatx4 au[2][4];
  #pragma unroll
  for (int rt = 0; rt < 2; ++rt)
    #pragma unroll
    for (int ct = 0; ct < 4; ++ct) {
      au[rt][ct] = (floatx4){0.f,0.f,0.f,0.f};
      if (rt < nvt)
        #pragma unroll
        for (int r = 0; r < 4; ++r) {
          int lrow = rh2*32 + rt*16 + q*4 + r;
          au[rt][ct][r] = tabU[id_s[lrow]*128 + colg[ct]];
        }
    }
  #pragma unroll
  for (int kb = 0; kb < 4; ++kb) {
    uint4 bb[4];
    #pragma unroll
    for (int ct = 0; ct < 4; ++ct) bb[ct] = *(const uint4*)(wum + colg[ct]*64 + kb*16 + q*4);
    #pragma unroll
    for (int rt = 0; rt < 2; ++rt)
      if (rt < nvt) {
        uint4 a = *(const uint4*)&m_a[arowi[rt]*68 + kb*16 + q*4];
        #pragma unroll
        for (int ct = 0; ct < 4; ++ct)
          au[rt][ct] = __builtin_amdgcn_mfma_f32_16x16x32_bf16(as_s8(a), as_s8(bb[ct]), au[rt][ct], 0, 0, 0);
      }
  }
  __syncthreads();   // B4

  {
    float buv[4];
    #pragma unroll
    for (int ct = 0; ct < 4; ++ct) buv[ct] = bu_s[colg[ct]];
    #pragma unroll
    for (int rt = 0; rt < 2; ++rt)
      if (rt < nvt)
        #pragma unroll
        for (int ct = 0; ct < 4; ++ct)
          #pragma unroll
          for (int r = 0; r < 4; ++r) {
            int lrow = rh2*32 + rt*16 + q*4 + r;
            m16[lrow*136 + colg[ct]] = bf16_1(fmaxf(au[rt][ct][r] + buv[ct], 0.f));
          }
  }
  __syncthreads();   // B5
  #pragma unroll
  for (int it = 0; it < 4; ++it) {
    int f = it*256 + t;
    int lr = f >> 4, c4 = (f & 15) * 4;
    if (row0 + lr < vn)
      *(uint4*)&eblk[(size_t)(row0 + lr)*64 + c4] = *(const uint4*)&m_a[lr*68 + c4];
  }
}

// ---------- edge rounds >=1: 3 MFMA passes, LDS-staged E, 64-row half-blocks ----------
__global__ __launch_bounds__(256,4) void edge_round_rest(
  unsigned* __restrict__ eg,
  const unsigned* __restrict__ wT,
  const float* __restrict__ a_l, const float* __restrict__ b_l,
  const float* __restrict__ a_m, const float* __restrict__ b_m,
  const float* __restrict__ bl1, const float* __restrict__ wl2,
  const float* __restrict__ bl2, const float* __restrict__ bm,
  const float* __restrict__ bu,
  const int* __restrict__ event_nums,
  float* __restrict__ ms0, float* __restrict__ ms1)
{
  __shared__ unsigned e_s[64*68];
  __shared__ unsigned m_a[64*68];
  __shared__ float adj[64], msum[128];
  __shared__ float bL_s[128], bM_s[128], bu_s[128], wl2_s[128];
  unsigned short* m16 = (unsigned short*)m_a;

  const int t = threadIdx.x;
  int b, j, half;
  decode_blk(blockIdx.x, b, j, half);
  const int vn = event_nums[b];
  const int row0 = half*64;
  int vnl = vn - row0; vnl = vnl < 0 ? 0 : (vnl > 64 ? 64 : vnl);
  if (j >= vn || vnl == 0) return;

  unsigned* eblk = eg + (size_t)(b*128 + j) * 8192;
  const float bl2v = bl2[0];

  if (t < 128) {
    bL_s[t] = b_l[(size_t)(b*128 + j)*128 + t] + bl1[t];
    bM_s[t] = b_m[(size_t)(b*128 + j)*128 + t] + bm[t];
    bu_s[t] = bu[t];
    wl2_s[t] = wl2[t];
    msum[t] = 0.f;
  }
  if (t < 64) adj[t] = 0.f;
  {
    const int vnc16 = (vnl + 15) & ~15;
    const int srow = t >> 4, c4 = (t & 15) * 4;
    #pragma unroll
    for (int it = 0; it < 4; ++it) {
      int lr = it*16 + srow;
      if (lr < vnc16)
        *(uint4*)&e_s[lr*68 + c4] = *(const uint4*)&eblk[(size_t)(row0 + lr)*64 + c4];
    }
  }

  const int lane = t & 63, wv = t >> 6;
  const int q = lane >> 4, n = lane & 15;
  const int rh2 = wv >> 1, ch = wv & 1;

  int nvt = (vnl - rh2*32 + 15) >> 4;
  nvt = nvt < 0 ? 0 : (nvt > 2 ? 2 : nvt);

  const unsigned* wz  = wT;
  const unsigned* wm  = wT + 8192;
  const unsigned* wue = wT + 16384;
  const unsigned* wum = wT + 24576;

  int colg[4];
  #pragma unroll
  for (int ct = 0; ct < 4; ++ct) colg[ct] = ch*64 + ct*16 + n;
  int arowi[2];
  #pragma unroll
  for (int rt = 0; rt < 2; ++rt) arowi[rt] = rh2*32 + rt*16 + n;

  // Prefetch a_l into registers pre-B1: latency hides under staging + Z MFMA.
  const float* aLb = a_l + (size_t)(b*128 + row0)*128;
  const float* aMb = a_m + (size_t)(b*128 + row0)*128;
  float alv[2][4][4];
  #pragma unroll
  for (int rt = 0; rt < 2; ++rt)
    if (rt < nvt)
      #pragma unroll
      for (int ct = 0; ct < 4; ++ct)
        #pragma unroll
        for (int r = 0; r < 4; ++r) {
          int lrow = rh2*32 + rt*16 + q*4 + r;
          alv[rt][ct][r] = aLb[(size_t)lrow*128 + colg[ct]];
        }
  __syncthreads();   // B1

  // ---------- PASS Z ----------
  floatx4 az[2][4];
  #pragma unroll
  for (int rt = 0; rt < 2; ++rt)
    #pragma unroll
    for (int ct = 0; ct < 4; ++ct) az[rt][ct] = (floatx4){0.f,0.f,0.f,0.f};
  #pragma unroll
  for (int kp = 0; kp < 2; ++kp) {   // two kb per iteration: 8 B-loads in flight
    uint4 bb[2][4];
    #pragma unroll
    for (int k2 = 0; k2 < 2; ++k2)
      #pragma unroll
      for (int ct = 0; ct < 4; ++ct)
        bb[k2][ct] = *(const uint4*)(wz + colg[ct]*64 + (kp*2 + k2)*16 + q*4);
    #pragma unroll
    for (int k2 = 0; k2 < 2; ++k2)
      #pragma unroll
      for (int rt = 0; rt < 2; ++rt)
        if (rt < nvt) {
          uint4 a = *(const uint4*)&e_s[arowi[rt]*68 + (kp*2 + k2)*16 + q*4];
          #pragma unroll
          for (int ct = 0; ct < 4; ++ct)
            az[rt][ct] = __builtin_amdgcn_mfma_f32_16x16x32_bf16(as_s8(a), as_s8(bb[k2][ct]), az[rt][ct], 0, 0, 0);
        }
  }

  // Z epilogue (consume prefetched alv)
  {
    float wl2v[4], bLv[4];
    #pragma unroll
    for (int ct = 0; ct < 4; ++ct) { wl2v[ct] = wl2_s[colg[ct]]; bLv[ct] = bL_s[colg[ct]]; }
    #pragma unroll
    for (int rt = 0; rt < 2; ++rt) {
      if (rt < nvt) {
        float szr[4] = {0.f,0.f,0.f,0.f};
        #pragma unroll
        for (int ct = 0; ct < 4; ++ct) {
          #pragma unroll
          for (int r = 0; r < 4; ++r) {
            float zv = fmaxf(az[rt][ct][r] + alv[rt][ct][r] + bLv[ct], 0.f);
            szr[r] += zv * wl2v[ct];
          }
        }
        #pragma unroll
        for (int r = 0; r < 4; ++r) {
          szr[r] += __shfl_xor(szr[r], 1);
          szr[r] += __shfl_xor(szr[r], 2);
          szr[r] += __shfl_xor(szr[r], 4);
          szr[r] += __shfl_xor(szr[r], 8);
        }
        if (n == 0) {
          #pragma unroll
          for (int r = 0; r < 4; ++r)
            atomicAdd(&adj[rh2*32 + rt*16 + q*4 + r], szr[r]);
        }
      }
    }
  }

  // Prefetch a_m now (alv dead): latency hides under B2 + M MFMA.
  float amv[2][4][4];
  #pragma unroll
  for (int rt = 0; rt < 2; ++rt)
    if (rt < nvt)
      #pragma unroll
      for (int ct = 0; ct < 4; ++ct)
        #pragma unroll
        for (int r = 0; r < 4; ++r) {
          int lrow = rh2*32 + rt*16 + q*4 + r;
          amv[rt][ct][r] = aMb[(size_t)lrow*128 + colg[ct]];
        }
  __syncthreads();   // B2: adj final

  // ---------- PASS M ----------
  floatx4 am[2][4];
  #pragma unroll
  for (int rt = 0; rt < 2; ++rt)
    #pragma unroll
    for (int ct = 0; ct < 4; ++ct) am[rt][ct] = (floatx4){0.f,0.f,0.f,0.f};
  #pragma unroll
  for (int kp = 0; kp < 2; ++kp) {
    uint4 bb[2][4];
    #pragma unroll
    for (int k2 = 0; k2 < 2; ++k2)
      #pragma unroll
      for (int ct = 0; ct < 4; ++ct)
        bb[k2][ct] = *(const uint4*)(wm + colg[ct]*64 + (kp*2 + k2)*16 + q*4);
    #pragma unroll
    for (int k2 = 0; k2 < 2; ++k2)
      #pragma unroll
      for (int rt = 0; rt < 2; ++rt)
        if (rt < nvt) {
          uint4 a = *(const uint4*)&e_s[arowi[rt]*68 + (kp*2 + k2)*16 + q*4];
          #pragma unroll
          for (int ct = 0; ct < 4; ++ct)
            am[rt][ct] = __builtin_amdgcn_mfma_f32_16x16x32_bf16(as_s8(a), as_s8(bb[k2][ct]), am[rt][ct], 0, 0, 0);
        }
  }

  // M epilogue (consume prefetched amv; per-thread sigmoid)
  {
    float bMv[4];
    #pragma unroll
    for (int ct = 0; ct < 4; ++ct) bMv[ct] = bM_s[colg[ct]];
    float colsum[4] = {0.f,0.f,0.f,0.f};
    #pragma unroll
    for (int rt = 0; rt < 2; ++rt) {
      if (rt < nvt) {
        #pragma unroll
        for (int r = 0; r < 4; ++r) {
          int lrow = rh2*32 + rt*16 + q*4 + r;
          float sc = (lrow < vnl) ? sigf(adj[lrow] + bl2v) : 0.f;
          #pragma unroll
          for (int ct = 0; ct < 4; ++ct) {
            float mv = fmaxf(am[rt][ct][r] + amv[rt][ct][r] + bMv[ct], 0.f) * sc;
            m16[lrow*136 + colg[ct]] = bf16_1(mv);
            colsum[ct] += mv;
          }
        }
      }
    }
    #pragma unroll
    for (int ct = 0; ct < 4; ++ct) {
      float v = colsum[ct];
      v += __shfl_xor(v, 16);
      v += __shfl_xor(v, 32);
      if (lane < 16) atomicAdd(&msum[colg[ct]], v);
    }
  }
  __syncthreads();   // B3
  {
    float* msH = half ? ms1 : ms0;
    if (t < 128) msH[(size_t)(b*128 + j)*128 + t] = msum[t];   // exclusive owner
  }

  // ---------- PASS U ----------
  floatx4 au[2][4];
  #pragma unroll
  for (int rt = 0; rt < 2; ++rt)
    #pragma unroll
    for (int ct = 0; ct < 4; ++ct) au[rt][ct] = (floatx4){0.f,0.f,0.f,0.f};
  #pragma unroll
  for (int kp = 0; kp < 2; ++kp) {
    uint4 bb[2][4];
    #pragma unroll
    for (int k2 = 0; k2 < 2; ++k2)
      #pragma unroll
      for (int ct = 0; ct < 4; ++ct)
        bb[k2][ct] = *(const uint4*)(wue + colg[ct]*64 + (kp*2 + k2)*16 + q*4);
    #pragma unroll
    for (int k2 = 0; k2 < 2; ++k2)
      #pragma unroll
      for (int rt = 0; rt < 2; ++rt)
        if (rt < nvt) {
          uint4 a = *(const uint4*)&e_s[arowi[rt]*68 + (kp*2 + k2)*16 + q*4];
          #pragma unroll
          for (int ct = 0; ct < 4; ++ct)
            au[rt][ct] = __builtin_amdgcn_mfma_f32_16x16x32_bf16(as_s8(a), as_s8(bb[k2][ct]), au[rt][ct], 0, 0, 0);
        }
  }
  #pragma unroll
  for (int kp = 0; kp < 2; ++kp) {
    uint4 bb[2][4];
    #pragma unroll
    for (int k2 = 0; k2 < 2; ++k2)
      #pragma unroll
      for (int ct = 0; ct < 4; ++ct)
        bb[k2][ct] = *(const uint4*)(wum + colg[ct]*64 + (kp*2 + k2)*16 + q*4);
    #pragma unroll
    for (int k2 = 0; k2 < 2; ++k2)
      #pragma unroll
      for (int rt = 0; rt < 2; ++rt)
        if (rt < nvt) {
          uint4 a = *(const uint4*)&m_a[arowi[rt]*68 + (kp*2 + k2)*16 + q*4];
          #pragma unroll
          for (int ct = 0; ct < 4; ++ct)
            au[rt][ct] = __builtin_amdgcn_mfma_f32_16x16x32_bf16(as_s8(a), as_s8(bb[k2][ct]), au[rt][ct], 0, 0, 0);
        }
  }
  __syncthreads();   // B4

  {
    float buv[4];
    #pragma unroll
    for (int ct = 0; ct < 4; ++ct) buv[ct] = bu_s[colg[ct]];
    #pragma unroll
    for (int rt = 0; rt < 2; ++rt)
      if (rt < nvt)
        #pragma unroll
        for (int ct = 0; ct < 4; ++ct)
          #pragma unroll
          for (int r = 0; r < 4; ++r) {
            int lrow = rh2*32 + rt*16 + q*4 + r;
            m16[lrow*136 + colg[ct]] = bf16_1(fmaxf(au[rt][ct][r] + buv[ct], 0.f));
          }
  }
  __syncthreads();   // B5
  #pragma unroll
  for (int it = 0; it < 4; ++it) {
    int f = it*256 + t;
    int lr = f >> 4, c4 = (f & 15) * 4;
    if (row0 + lr < vn)
      *(uint4*)&eblk[(size_t)(row0 + lr)*64 + c4] = *(const uint4*)&m_a[lr*68 + c4];
  }
}

// ---------- MFMA readout, both GEMMs on matrix cores ----------
__global__ __launch_bounds__(256,4) void readout_mfma(
  const unsigned* __restrict__ eg,
  const unsigned* __restrict__ wr1T,
  const unsigned* __restrict__ wr2T,
  const float* __restrict__ br1, const float* __restrict__ br2,
  const int* __restrict__ event_nums, float* __restrict__ out)
{
  __shared__ unsigned f_s[64*132];
  __shared__ int iu_s[64], ju_s[64];
  unsigned short* h16 = (unsigned short*)f_s;

  const int t = threadIdx.x;
  const int b = blockIdx.x / 127, pb = blockIdx.x % 127;
  const int vn = event_nums[b];

  if (t < 64) {
    int p = pb*64 + t;
    float disc = (float)((2*NN-1)*(2*NN-1) - 8*p);
    int iu = (int)(((float)(2*NN-1) - sqrtf(disc)) * 0.5f);
    if (iu < 0) iu = 0; if (iu > NN-2) iu = NN-2;
    while (iu < NN-2 && ((iu+1)*(2*NN-2-iu))/2 <= p) ++iu;
    while (iu > 0 && (iu*(2*NN-1-iu))/2 > p) --iu;
    int ju = p - (iu*(2*NN-1-iu))/2 + iu + 1;
    iu_s[t] = iu; ju_s[t] = ju;
  }
  __syncthreads();

  #pragma unroll
  for (int it = 0; it < 8; ++it) {
    int f4 = it*1024 + t*4;
    int pr = f4 >> 7, w = f4 & 127;
    int side = w >> 6, k2 = w & 63;
    int iu = iu_s[pr], ju = ju_s[pr];
    size_t base = side ? (((size_t)(b*128 + iu))*128 + ju)*64
                       : (((size_t)(b*128 + ju))*128 + iu)*64;
    *(uint4*)&f_s[pr*132 + w] = *(const uint4*)&eg[base + k2];
  }
  __syncthreads();

  const int lane = t & 63, wv = t >> 6;
  const int q = lane >> 4, n = lane & 15;
  int colg[4];
  #pragma unroll
  for (int ct = 0; ct < 4; ++ct) colg[ct] = wv*64 + ct*16 + n;

  floatx4 acc[4][4];
  #pragma unroll
  for (int rt = 0; rt < 4; ++rt)
    #pragma unroll
    for (int ct = 0; ct < 4; ++ct) acc[rt][ct] = (floatx4){0.f,0.f,0.f,0.f};

  #pragma unroll
  for (int kb = 0; kb < 8; ++kb) {
    uint4 bb[4];
    #pragma unroll
    for (int ct = 0; ct < 4; ++ct) bb[ct] = *(const uint4*)(wr1T + (size_t)colg[ct]*128 + kb*16 + q*4);
    #pragma unroll
    for (int rt = 0; rt < 4; ++rt) {
      uint4 a = *(const uint4*)&f_s[(rt*16 + n)*132 + kb*16 + q*4];
      #pragma unroll
      for (int ct = 0; ct < 4; ++ct)
        acc[rt][ct] = __builtin_amdgcn_mfma_f32_16x16x32_bf16(as_s8(a), as_s8(bb[ct]), acc[rt][ct], 0, 0, 0);
    }
  }
  __syncthreads();

  {
    float brv[4];
    #pragma unroll
    for (int ct = 0; ct < 4; ++ct) brv[ct] = br1[colg[ct]];
    #pragma unroll
    for (int rt = 0; rt < 4; ++rt)
      #pragma unroll
      for (int ct = 0; ct < 4; ++ct)
        #pragma unroll
        for (int r = 0; r < 4; ++r) {
          int pr = rt*16 + q*4 + r;
          h16[pr*264 + colg[ct]] = bf16_1(fmaxf(acc[rt][ct][r] + brv[ct], 0.f));
        }
  }
  __syncthreads();

  floatx4 acc2 = (floatx4){0.f,0.f,0.f,0.f};
  #pragma unroll
  for (int kb = 0; kb < 8; ++kb) {
    uint4 bb = *(const uint4*)(wr2T + n*128 + kb*16 + q*4);
    uint4 a  = *(const uint4*)&f_s[(wv*16 + n)*132 + kb*16 + q*4];
    acc2 = __builtin_amdgcn_mfma_f32_16x16x32_bf16(as_s8(a), as_s8(bb), acc2, 0, 0, 0);
  }

  if (n < 10) {
    float bias = br2[n];
    #pragma unroll
    for (int r = 0; r < 4; ++r) {
      int pr = wv*16 + q*4 + r;
      int iu = iu_s[pr], ju = ju_s[pr];
      if (ju < vn) {
        int idx = iu*vn - (iu*(iu+1))/2 + (ju - iu - 1);
        out[(((size_t)b*5 + (n>>1))*PP + idx)*2 + (n&1)] = acc2[r] + bias;
      }
    }
  }
}

extern "C" void kernel_launch(void* const* d_in, const int* in_sizes, int n_in,
                              void* d_out, int out_size, void* d_ws, size_t ws_size,
                              hipStream_t stream) {
  const int*   edge_ids      = (const int*)d_in[0];
  const float* node_features = (const float*)d_in[1];
  const int*   event_nums    = (const int*)d_in[3];
  const float* emb  = (const float*)d_in[4];
  const float* Wl_e = (const float*)d_in[5];
  const float* Wl_w = (const float*)d_in[6];
  const float* Wl_v = (const float*)d_in[7];
  const float* bl1  = (const float*)d_in[8];
  const float* wl2  = (const float*)d_in[9];
  const float* bl2  = (const float*)d_in[10];
  const float* Wm_w = (const float*)d_in[11];
  const float* Wm_v = (const float*)d_in[12];
  const float* Wm_e = (const float*)d_in[13];
  const float* bm   = (const float*)d_in[14];
  const float* Wu_e = (const float*)d_in[15];
  const float* Wu_m = (const float*)d_in[16];
  const float* bu   = (const float*)d_in[17];
  const float* W_ih = (const float*)d_in[18];
  const float* W_hh = (const float*)d_in[19];
  const float* b_ih = (const float*)d_in[20];
  const float* b_hh = (const float*)d_in[21];
  const float* Wr1  = (const float*)d_in[22];
  const float* br1  = (const float*)d_in[23];
  const float* Wr2  = (const float*)d_in[24];
  const float* br2  = (const float*)d_in[25];

  const size_t SZ_E = (size_t)134217728;       // B*N*N*64 u32
  const size_t SZ_S = (size_t)2097152;         // B*N*128 f32
  const size_t SZ_W = (size_t)131072;          // 32768 u32
  const size_t SZ_W2 = (size_t)8192;           // 2048 u32
  const size_t SZ_TAB = (size_t)2048;          // 512 f32 each
  const size_t need = SZ_E + 7*SZ_S + 2*SZ_W + SZ_W2 + 3*SZ_TAB;

  hipMemsetAsync(d_out, 0, (size_t)out_size * sizeof(float), stream);
  if (ws_size < need) return;

  char* w = (char*)d_ws;
  unsigned* eg   = (unsigned*)w; w += SZ_E;
  float* h_ws = (float*)w; w += SZ_S;
  float* a_l  = (float*)w; w += SZ_S;
  float* b_l  = (float*)w; w += SZ_S;
  float* a_m  = (float*)w; w += SZ_S;
  float* b_m  = (float*)w; w += SZ_S;
  float* ms0  = (float*)w; w += SZ_S;
  float* ms1  = (float*)w; w += SZ_S;
  unsigned* wT   = (unsigned*)w; w += SZ_W;
  unsigned* wr1T = (unsigned*)w; w += SZ_W;
  unsigned* wr2T = (unsigned*)w; w += SZ_W2;
  float* embZ = (float*)w; w += SZ_TAB;
  float* embM = (float*)w; w += SZ_TAB;
  float* embU = (float*)w; w += SZ_TAB;

  hipLaunchKernelGGL(conv_w_kernel, dim3(256), dim3(256), 0, stream,
      Wl_e, Wm_e, Wu_e, Wu_m, Wr1, Wr2, emb, wT, wr1T, wr2T, embZ, embM, embU);

  hipLaunchKernelGGL(gru_proj_kernel, dim3(1024), dim3(256), 0, stream,
      0, ms0, ms1, node_features, h_ws, W_ih, W_hh, b_ih, b_hh,
      Wl_w, Wl_v, Wm_w, Wm_v, event_nums, a_l, b_l, a_m, b_m);

  for (int r = 0; r < 3; ++r) {
    if (r == 0) {
      hipLaunchKernelGGL(edge_round_first, dim3(8192), dim3(256), 0, stream,
          eg, wT, edge_ids, embZ, embM, embU,
          a_l, b_l, a_m, b_m, bl1, wl2, bl2, bm, bu, event_nums, ms0, ms1);
    } else {
      hipLaunchKernelGGL(edge_round_rest, dim3(8192), dim3(256), 0, stream,
          eg, wT, a_l, b_l, a_m, b_m, bl1, wl2, bl2, bm, bu, event_nums, ms0, ms1);
    }
    if (r < 2) {
      const float* hin = (r == 0) ? node_features : h_ws;
      hipLaunchKernelGGL(gru_proj_kernel, dim3(1024), dim3(256), 0, stream,
          1, ms0, ms1, hin, h_ws, W_ih, W_hh, b_ih, b_hh,
          Wl_w, Wl_v, Wm_w, Wm_v, event_nums, a_l, b_l, a_m, b_m);
    }
  }

  hipLaunchKernelGGL(readout_mfma, dim3(BB*127), dim3(256), 0, stream,
      eg, wr1T, wr2T, br1, br2, event_nums, (float*)d_out);
}

// Round 13
// 605.785 us; speedup vs baseline: 1.8506x; 1.2544x over previous
//
#include <hip/hip_runtime.h>
#include <cstddef>

// Problem constants
#define BB 32
#define NN 128
#define PP 8128

typedef __attribute__((ext_vector_type(8))) short short8;
typedef __attribute__((ext_vector_type(4))) float floatx4;

union U4S8 { uint4 u; short8 s; };
__device__ __forceinline__ short8 as_s8(uint4 v){ U4S8 x; x.u = v; return x.s; }

// ---------- bf16 helpers ----------
__device__ __forceinline__ unsigned pack_bf16(float a, float b){
  union{float f;unsigned u;}xa,xb; xa.f=a; xb.f=b;
  unsigned ua=xa.u, ub=xb.u;
  ua = (ua + 0x7fffu + ((ua>>16)&1u)) >> 16;
  ub = (ub + 0x7fffu + ((ub>>16)&1u)) >> 16;
  return (ua & 0xffffu) | (ub << 16);
}
__device__ __forceinline__ unsigned short bf16_1(float a){
  union{float f;unsigned u;}x; x.f=a;
  return (unsigned short)((x.u + 0x7fffu + ((x.u>>16)&1u)) >> 16);
}
__device__ __forceinline__ float sigf(float x){ return 1.f/(1.f + __expf(-x)); }

// Bijective block remap (kept from R5).
__device__ __forceinline__ void decode_blk(int gid, int& b, int& j, int& half){
  b    = ((gid>>11)&3)*8 + ((gid>>5)&7);
  j    = ((gid>>9)&3)*32 + (gid&31);
  half = (gid>>8)&1;
}

// ---------- weight conversion + round-0 tables (+ GRU/proj weights) ----------
// grid 576: blocks [0,256) = original sections; [256,576) = wih/whh/w4 conversions.
__global__ __launch_bounds__(256,4) void conv_w_kernel(
  const float* __restrict__ Wl_e, const float* __restrict__ Wm_e,
  const float* __restrict__ Wu_e, const float* __restrict__ Wu_m,
  const float* __restrict__ Wr1, const float* __restrict__ Wr2,
  const float* __restrict__ emb,
  const float* __restrict__ W_ih, const float* __restrict__ W_hh,
  const float* __restrict__ Wl_w, const float* __restrict__ Wl_v,
  const float* __restrict__ Wm_w, const float* __restrict__ Wm_v,
  unsigned* __restrict__ wT, unsigned* __restrict__ wr1T,
  unsigned* __restrict__ wr2T,
  float* __restrict__ embZ, float* __restrict__ embM, float* __restrict__ embU,
  unsigned* __restrict__ wihT, unsigned* __restrict__ whhT,
  unsigned* __restrict__ w4T)
{
  int tid = blockIdx.x*256 + threadIdx.x;
  if (tid < 65536) {
    if (tid < 2048) {   // Wr2 [256][10] -> B-frag layout [16 cols][128 k2], zero-padded
      int c = tid >> 7, k2 = tid & 127;
      unsigned v = 0;
      if (c < 10) v = pack_bf16(Wr2[(2*k2)*10 + c], Wr2[(2*k2+1)*10 + c]);
      wr2T[c*128 + k2] = v;
    }
    if (tid >= 4096 && tid < 5632) {   // round-0 tables: emb(4x128) @ W(128x128), f32
      int idx = tid - 4096;            // 0..1535
      int tb = idx >> 9;               // 0..2
      int r  = idx & 511;
      int id = r >> 7, c = r & 127;
      const float* W = (tb==0) ? Wl_e : (tb==1) ? Wm_e : Wu_e;
      float s = 0.f;
      #pragma unroll 4
      for (int k = 0; k < 128; ++k) s += emb[id*128 + k] * W[(size_t)k*128 + c];
      float* T = (tb==0) ? embZ : (tb==1) ? embM : embU;
      T[r] = s;
    }
    if (tid < 32768) {
      int mat = tid >> 13, r = tid & 8191;
      int k2 = r >> 7, c = r & 127;
      const float* W = (mat==0) ? Wl_e : (mat==1) ? Wm_e : (mat==2) ? Wu_e : Wu_m;
      wT[mat*8192 + c*64 + k2] = pack_bf16(W[(2*k2)*128 + c], W[(2*k2+1)*128 + c]);
    } else {
      int r = tid - 32768;
      int k2 = r >> 8, c = r & 255;
      wr1T[(size_t)c*128 + k2] = pack_bf16(Wr1[(2*k2)*256 + c], Wr1[(2*k2+1)*256 + c]);
    }
  } else {
    int t2 = tid - 65536;              // 0..81919
    if (t2 < 24576) {                  // W_ih [128][384] -> wihT[c*64+k2]
      int c = t2 >> 6, k2 = t2 & 63;
      wihT[c*64 + k2] = pack_bf16(W_ih[(size_t)(2*k2)*384 + c], W_ih[(size_t)(2*k2+1)*384 + c]);
    } else if (t2 < 49152) {           // W_hh [128][384]
      int r = t2 - 24576;
      int c = r >> 6, k2 = r & 63;
      whhT[c*64 + k2] = pack_bf16(W_hh[(size_t)(2*k2)*384 + c], W_hh[(size_t)(2*k2+1)*384 + c]);
    } else if (t2 < 81920) {           // {Wl_w,Wl_v,Wm_w,Wm_v} [128][128]
      int r = t2 - 49152;
      int m = r >> 13, rr = r & 8191;
      int c = rr >> 6, k2 = rr & 63;
      const float* W = (m==0) ? Wl_w : (m==1) ? Wl_v : (m==2) ? Wm_w : Wm_v;
      w4T[m*8192 + c*64 + k2] = pack_bf16(W[(2*k2)*128 + c], W[(2*k2+1)*128 + c]);
    }
  }
}

// ---------- MFMA GRU + node projections ----------
// grid = 256: block = (b, 16-row group). Phase 1: gates via MFMA (6 fragments/wave),
// h_new in f32 with exact f32 `hold`. Phase 2: projections h_new @ W4 via MFMA
// (wave wv owns output matrix wv: no runtime-indexed pointers).
__global__ __launch_bounds__(256,4) void gru_mfma(
  int do_gru,
  const float* __restrict__ ms0, const float* __restrict__ ms1,
  const float* __restrict__ h_in, float* __restrict__ h_out,
  const unsigned* __restrict__ wihT, const unsigned* __restrict__ whhT,
  const unsigned* __restrict__ w4T,
  const float* __restrict__ b_ih, const float* __restrict__ b_hh,
  const int* __restrict__ event_nums,
  float* __restrict__ a_l, float* __restrict__ b_l,
  float* __restrict__ a_m, float* __restrict__ b_m)
{
  __shared__ unsigned msT[16*68], hT[16*68], hnT[16*68];
  unsigned short* hn16 = (unsigned short*)hnT;

  const int t = threadIdx.x;
  const int bg = blockIdx.x;
  const int b = bg >> 3, row0 = (bg & 7) * 16;
  const int vn = event_nums[b];
  const int lane = t & 63, wv = t >> 6;
  const int q = lane >> 4, n = lane & 15;

  // stage inputs to bf16 LDS A-tiles (16 rows x 64 u32)
  #pragma unroll
  for (int i = 0; i < 4; ++i) {
    int idx = i*256 + t;               // 0..1023
    int r = idx >> 6, c2 = idx & 63;
    size_t base = ((size_t)(b*128 + row0 + r))*128 + 2*c2;
    if (do_gru) {
      float m0 = ms0[base], m1 = ms0[base + 1];
      if (vn > 64) { m0 += ms1[base]; m1 += ms1[base + 1]; }
      msT[r*68 + c2] = pack_bf16(m0, m1);
      hT[r*68 + c2]  = pack_bf16(h_in[base], h_in[base + 1]);
    } else {
      hnT[r*68 + c2] = pack_bf16(h_in[base], h_in[base + 1]);
    }
  }
  __syncthreads();

  if (do_gru) {
    #pragma unroll
    for (int cc = 0; cc < 2; ++cc) {
      int c = (wv*2 + cc)*16 + n;      // absolute gate/h column
      floatx4 air = (floatx4){0.f,0.f,0.f,0.f};
      floatx4 aiz = (floatx4){0.f,0.f,0.f,0.f};
      floatx4 ain = (floatx4){0.f,0.f,0.f,0.f};
      floatx4 ahr = (floatx4){0.f,0.f,0.f,0.f};
      floatx4 ahz = (floatx4){0.f,0.f,0.f,0.f};
      floatx4 ahn = (floatx4){0.f,0.f,0.f,0.f};
      #pragma unroll
      for (int kb = 0; kb < 4; ++kb) {
        uint4 ma = *(const uint4*)&msT[n*68 + kb*16 + q*4];
        uint4 ha = *(const uint4*)&hT[n*68 + kb*16 + q*4];
        uint4 b0 = *(const uint4*)(wihT + (size_t)c*64        + kb*16 + q*4);
        uint4 b1 = *(const uint4*)(wihT + (size_t)(128+c)*64  + kb*16 + q*4);
        uint4 b2 = *(const uint4*)(wihT + (size_t)(256+c)*64  + kb*16 + q*4);
        uint4 h0 = *(const uint4*)(whhT + (size_t)c*64        + kb*16 + q*4);
        uint4 h1 = *(const uint4*)(whhT + (size_t)(128+c)*64  + kb*16 + q*4);
        uint4 h2 = *(const uint4*)(whhT + (size_t)(256+c)*64  + kb*16 + q*4);
        air = __builtin_amdgcn_mfma_f32_16x16x32_bf16(as_s8(ma), as_s8(b0), air, 0, 0, 0);
        aiz = __builtin_amdgcn_mfma_f32_16x16x32_bf16(as_s8(ma), as_s8(b1), aiz, 0, 0, 0);
        ain = __builtin_amdgcn_mfma_f32_16x16x32_bf16(as_s8(ma), as_s8(b2), ain, 0, 0, 0);
        ahr = __builtin_amdgcn_mfma_f32_16x16x32_bf16(as_s8(ha), as_s8(h0), ahr, 0, 0, 0);
        ahz = __builtin_amdgcn_mfma_f32_16x16x32_bf16(as_s8(ha), as_s8(h1), ahz, 0, 0, 0);
        ahn = __builtin_amdgcn_mfma_f32_16x16x32_bf16(as_s8(ha), as_s8(h2), ahn, 0, 0, 0);
      }
      float bi0 = b_ih[c], bi1 = b_ih[128 + c], bi2 = b_ih[256 + c];
      float bh0 = b_hh[c], bh1 = b_hh[128 + c], bh2 = b_hh[256 + c];
      #pragma unroll
      for (int r = 0; r < 4; ++r) {
        int node = row0 + q*4 + r;
        size_t gidx = ((size_t)(b*128 + node))*128 + c;
        float hold = h_in[gidx];
        float rr = sigf(air[r] + bi0 + ahr[r] + bh0);
        float zg = sigf(aiz[r] + bi1 + ahz[r] + bh1);
        float nn = tanhf(ain[r] + bi2 + rr*(ahn[r] + bh2));
        float hv = (node < vn) ? (1.f - zg)*nn + zg*hold : hold;
        h_out[gidx] = hv;
        hn16[(q*4 + r)*136 + c] = bf16_1(hv);
      }
    }
    __syncthreads();   // hnT final
  }

  // phase 2: projections hnT @ w4T. Wave wv owns matrix wv (128 cols = 8 col-tiles).
  float* Out = (wv == 0) ? a_l : (wv == 1) ? b_l : (wv == 2) ? a_m : b_m;
  #pragma unroll
  for (int g = 0; g < 2; ++g) {
    floatx4 acc[4];
    #pragma unroll
    for (int c4 = 0; c4 < 4; ++c4) acc[c4] = (floatx4){0.f,0.f,0.f,0.f};
    #pragma unroll
    for (int kb = 0; kb < 4; ++kb) {
      uint4 a = *(const uint4*)&hnT[n*68 + kb*16 + q*4];
      #pragma unroll
      for (int c4 = 0; c4 < 4; ++c4) {
        int ct = wv*8 + g*4 + c4;       // global 16-col tile in [0,32)
        uint4 bb = *(const uint4*)(w4T + (size_t)(ct*16 + n)*64 + kb*16 + q*4);
        acc[c4] = __builtin_amdgcn_mfma_f32_16x16x32_bf16(as_s8(a), as_s8(bb), acc[c4], 0, 0, 0);
      }
    }
    #pragma unroll
    for (int c4 = 0; c4 < 4; ++c4) {
      int c = (g*4 + c4)*16 + n;        // column within this wave's matrix
      #pragma unroll
      for (int r = 0; r < 4; ++r) {
        int node = row0 + q*4 + r;
        Out[((size_t)(b*128 + node))*128 + c] = acc[c4][r];
      }
    }
  }
}

// ---------- edge round 0: table-driven (no E GEMMs), only M@Wu_m on MFMA ----------
__global__ __launch_bounds__(256,4) void edge_round_first(
  unsigned* __restrict__ eg,
  const unsigned* __restrict__ wT,     // need wum = wT+24576
  const int* __restrict__ ids,
  const float* __restrict__ embZ, const float* __restrict__ embM,
  const float* __restrict__ embU,
  const float* __restrict__ a_l, const float* __restrict__ b_l,
  const float* __restrict__ a_m, const float* __restrict__ b_m,
  const float* __restrict__ bl1, const float* __restrict__ wl2,
  const float* __restrict__ bl2, const float* __restrict__ bm,
  const float* __restrict__ bu,
  const int* __restrict__ event_nums,
  float* __restrict__ ms0, float* __restrict__ ms1)
{
  __shared__ unsigned m_a[64*68];
  __shared__ float adj[64], msum[128];
  __shared__ float bL_s[128], bM_s[128], bu_s[128], wl2_s[128];
  __shared__ float tabZ[512], tabM[512], tabU[512];
  __shared__ int id_s[64];
  unsigned short* m16 = (unsigned short*)m_a;

  const int t = threadIdx.x;
  int b, j, half;
  decode_blk(blockIdx.x, b, j, half);
  const int vn = event_nums[b];
  const int row0 = half*64;
  int vnl = vn - row0; vnl = vnl < 0 ? 0 : (vnl > 64 ? 64 : vnl);
  if (j >= vn || vnl == 0) return;

  unsigned* eblk = eg + (size_t)(b*128 + j) * 8192;
  const float bl2v = bl2[0];

  if (t < 128) {
    bL_s[t] = b_l[(size_t)(b*128 + j)*128 + t] + bl1[t];
    bM_s[t] = b_m[(size_t)(b*128 + j)*128 + t] + bm[t];
    bu_s[t] = bu[t];
    wl2_s[t] = wl2[t];
    msum[t] = 0.f;
  }
  if (t < 64) {
    adj[t] = 0.f;
    id_s[t] = ids[((size_t)(b*128 + row0 + t))*128 + j];
  }
  for (int i = t; i < 512; i += 256) {
    tabZ[i] = embZ[i]; tabM[i] = embM[i]; tabU[i] = embU[i];
  }

  const int lane = t & 63, wv = t >> 6;
  const int q = lane >> 4, n = lane & 15;
  const int rh2 = wv >> 1, ch = wv & 1;

  int nvt = (vnl - rh2*32 + 15) >> 4;
  nvt = nvt < 0 ? 0 : (nvt > 2 ? 2 : nvt);

  const unsigned* wum = wT + 24576;
  int colg[4];
  #pragma unroll
  for (int ct = 0; ct < 4; ++ct) colg[ct] = ch*64 + ct*16 + n;
  int arowi[2];
  #pragma unroll
  for (int rt = 0; rt < 2; ++rt) arowi[rt] = rh2*32 + rt*16 + n;

  // Prefetch a_l / a_m into registers (hide L2/L3 latency under barrier + tables)
  const float* aLb = a_l + (size_t)(b*128 + row0)*128;
  const float* aMb = a_m + (size_t)(b*128 + row0)*128;
  float alv[2][4][4], amv[2][4][4];
  #pragma unroll
  for (int rt = 0; rt < 2; ++rt)
    if (rt < nvt)
      #pragma unroll
      for (int ct = 0; ct < 4; ++ct)
        #pragma unroll
        for (int r = 0; r < 4; ++r) {
          int lrow = rh2*32 + rt*16 + q*4 + r;
          alv[rt][ct][r] = aLb[(size_t)lrow*128 + colg[ct]];
          amv[rt][ct][r] = aMb[(size_t)lrow*128 + colg[ct]];
        }
  __syncthreads();   // B1

  // Z epilogue from tables
  {
    float wl2v[4], bLv[4];
    #pragma unroll
    for (int ct = 0; ct < 4; ++ct) { wl2v[ct] = wl2_s[colg[ct]]; bLv[ct] = bL_s[colg[ct]]; }
    #pragma unroll
    for (int rt = 0; rt < 2; ++rt) {
      if (rt < nvt) {
        float szr[4] = {0.f,0.f,0.f,0.f};
        #pragma unroll
        for (int ct = 0; ct < 4; ++ct) {
          #pragma unroll
          for (int r = 0; r < 4; ++r) {
            int lrow = rh2*32 + rt*16 + q*4 + r;
            float zv = fmaxf(tabZ[id_s[lrow]*128 + colg[ct]] + alv[rt][ct][r] + bLv[ct], 0.f);
            szr[r] += zv * wl2v[ct];
          }
        }
        #pragma unroll
        for (int r = 0; r < 4; ++r) {
          szr[r] += __shfl_xor(szr[r], 1);
          szr[r] += __shfl_xor(szr[r], 2);
          szr[r] += __shfl_xor(szr[r], 4);
          szr[r] += __shfl_xor(szr[r], 8);
        }
        if (n == 0) {
          #pragma unroll
          for (int r = 0; r < 4; ++r)
            atomicAdd(&adj[rh2*32 + rt*16 + q*4 + r], szr[r]);
        }
      }
    }
  }
  __syncthreads();   // B2: adj final

  // M epilogue from tables -> m16, msum (per-thread sigmoid, no svec)
  {
    float bMv[4];
    #pragma unroll
    for (int ct = 0; ct < 4; ++ct) bMv[ct] = bM_s[colg[ct]];
    float colsum[4] = {0.f,0.f,0.f,0.f};
    #pragma unroll
    for (int rt = 0; rt < 2; ++rt) {
      if (rt < nvt) {
        #pragma unroll
        for (int r = 0; r < 4; ++r) {
          int lrow = rh2*32 + rt*16 + q*4 + r;
          float sc = (lrow < vnl) ? sigf(adj[lrow] + bl2v) : 0.f;
          #pragma unroll
          for (int ct = 0; ct < 4; ++ct) {
            float mv = fmaxf(tabM[id_s[lrow]*128 + colg[ct]] + amv[rt][ct][r] + bMv[ct], 0.f) * sc;
            m16[lrow*136 + colg[ct]] = bf16_1(mv);
            colsum[ct] += mv;
          }
        }
      }
    }
    #pragma unroll
    for (int ct = 0; ct < 4; ++ct) {
      float v = colsum[ct];
      v += __shfl_xor(v, 16);
      v += __shfl_xor(v, 32);
      if (lane < 16) atomicAdd(&msum[colg[ct]], v);
    }
  }
  __syncthreads();   // B3
  {
    float* msH = half ? ms1 : ms0;
    if (t < 128) msH[(size_t)(b*128 + j)*128 + t] = msum[t];   // exclusive owner
  }

  // U = tabU gather + M@Wu_m
  floatx4 au[2][4];
  #pragma unroll
  for (int rt = 0; rt < 2; ++rt)
    #pragma unroll
    for (int ct = 0; ct < 4; ++ct) {
      au[rt][ct] = (floatx4){0.f,0.f,0.f,0.f};
      if (rt < nvt)
        #pragma unroll
        for (int r = 0; r < 4; ++r) {
          int lrow = rh2*32 + rt*16 + q*4 + r;
          au[rt][ct][r] = tabU[id_s[lrow]*128 + colg[ct]];
        }
    }
  #pragma unroll
  for (int kb = 0; kb < 4; ++kb) {
    uint4 bb[4];
    #pragma unroll
    for (int ct = 0; ct < 4; ++ct) bb[ct] = *(const uint4*)(wum + colg[ct]*64 + kb*16 + q*4);
    #pragma unroll
    for (int rt = 0; rt < 2; ++rt)
      if (rt < nvt) {
        uint4 a = *(const uint4*)&m_a[arowi[rt]*68 + kb*16 + q*4];
        #pragma unroll
        for (int ct = 0; ct < 4; ++ct)
          au[rt][ct] = __builtin_amdgcn_mfma_f32_16x16x32_bf16(as_s8(a), as_s8(bb[ct]), au[rt][ct], 0, 0, 0);
      }
  }
  __syncthreads();   // B4

  {
    float buv[4];
    #pragma unroll
    for (int ct = 0; ct < 4; ++ct) buv[ct] = bu_s[colg[ct]];
    #pragma unroll
    for (int rt = 0; rt < 2; ++rt)
      if (rt < nvt)
        #pragma unroll
        for (int ct = 0; ct < 4; ++ct)
          #pragma unroll
          for (int r = 0; r < 4; ++r) {
            int lrow = rh2*32 + rt*16 + q*4 + r;
            m16[lrow*136 + colg[ct]] = bf16_1(fmaxf(au[rt][ct][r] + buv[ct], 0.f));
          }
  }
  __syncthreads();   // B5
  #pragma unroll
  for (int it = 0; it < 4; ++it) {
    int f = it*256 + t;
    int lr = f >> 4, c4 = (f & 15) * 4;
    if (row0 + lr < vn)
      *(uint4*)&eblk[(size_t)(row0 + lr)*64 + c4] = *(const uint4*)&m_a[lr*68 + c4];
  }
}

// ---------- edge rounds >=1: 3 MFMA passes, LDS-staged E, 64-row half-blocks ----------
__global__ __launch_bounds__(256,4) void edge_round_rest(
  unsigned* __restrict__ eg,
  const unsigned* __restrict__ wT,
  const float* __restrict__ a_l, const float* __restrict__ b_l,
  const float* __restrict__ a_m, const float* __restrict__ b_m,
  const float* __restrict__ bl1, const float* __restrict__ wl2,
  const float* __restrict__ bl2, const float* __restrict__ bm,
  const float* __restrict__ bu,
  const int* __restrict__ event_nums,
  float* __restrict__ ms0, float* __restrict__ ms1)
{
  __shared__ unsigned e_s[64*68];
  __shared__ unsigned m_a[64*68];
  __shared__ float adj[64], msum[128];
  __shared__ float bL_s[128], bM_s[128], bu_s[128], wl2_s[128];
  unsigned short* m16 = (unsigned short*)m_a;

  const int t = threadIdx.x;
  int b, j, half;
  decode_blk(blockIdx.x, b, j, half);
  const int vn = event_nums[b];
  const int row0 = half*64;
  int vnl = vn - row0; vnl = vnl < 0 ? 0 : (vnl > 64 ? 64 : vnl);
  if (j >= vn || vnl == 0) return;

  unsigned* eblk = eg + (size_t)(b*128 + j) * 8192;
  const float bl2v = bl2[0];

  if (t < 128) {
    bL_s[t] = b_l[(size_t)(b*128 + j)*128 + t] + bl1[t];
    bM_s[t] = b_m[(size_t)(b*128 + j)*128 + t] + bm[t];
    bu_s[t] = bu[t];
    wl2_s[t] = wl2[t];
    msum[t] = 0.f;
  }
  if (t < 64) adj[t] = 0.f;
  {
    const int vnc16 = (vnl + 15) & ~15;
    const int srow = t >> 4, c4 = (t & 15) * 4;
    #pragma unroll
    for (int it = 0; it < 4; ++it) {
      int lr = it*16 + srow;
      if (lr < vnc16)
        *(uint4*)&e_s[lr*68 + c4] = *(const uint4*)&eblk[(size_t)(row0 + lr)*64 + c4];
    }
  }

  const int lane = t & 63, wv = t >> 6;
  const int q = lane >> 4, n = lane & 15;
  const int rh2 = wv >> 1, ch = wv & 1;

  int nvt = (vnl - rh2*32 + 15) >> 4;
  nvt = nvt < 0 ? 0 : (nvt > 2 ? 2 : nvt);

  const unsigned* wz  = wT;
  const unsigned* wm  = wT + 8192;
  const unsigned* wue = wT + 16384;
  const unsigned* wum = wT + 24576;

  int colg[4];
  #pragma unroll
  for (int ct = 0; ct < 4; ++ct) colg[ct] = ch*64 + ct*16 + n;
  int arowi[2];
  #pragma unroll
  for (int rt = 0; rt < 2; ++rt) arowi[rt] = rh2*32 + rt*16 + n;

  // Prefetch a_l into registers pre-B1: latency hides under staging + Z MFMA.
  const float* aLb = a_l + (size_t)(b*128 + row0)*128;
  const float* aMb = a_m + (size_t)(b*128 + row0)*128;
  float alv[2][4][4];
  #pragma unroll
  for (int rt = 0; rt < 2; ++rt)
    if (rt < nvt)
      #pragma unroll
      for (int ct = 0; ct < 4; ++ct)
        #pragma unroll
        for (int r = 0; r < 4; ++r) {
          int lrow = rh2*32 + rt*16 + q*4 + r;
          alv[rt][ct][r] = aLb[(size_t)lrow*128 + colg[ct]];
        }
  __syncthreads();   // B1

  // ---------- PASS Z ----------
  floatx4 az[2][4];
  #pragma unroll
  for (int rt = 0; rt < 2; ++rt)
    #pragma unroll
    for (int ct = 0; ct < 4; ++ct) az[rt][ct] = (floatx4){0.f,0.f,0.f,0.f};
  #pragma unroll
  for (int kp = 0; kp < 2; ++kp) {   // two kb per iteration: 8 B-loads in flight
    uint4 bb[2][4];
    #pragma unroll
    for (int k2 = 0; k2 < 2; ++k2)
      #pragma unroll
      for (int ct = 0; ct < 4; ++ct)
        bb[k2][ct] = *(const uint4*)(wz + colg[ct]*64 + (kp*2 + k2)*16 + q*4);
    #pragma unroll
    for (int k2 = 0; k2 < 2; ++k2)
      #pragma unroll
      for (int rt = 0; rt < 2; ++rt)
        if (rt < nvt) {
          uint4 a = *(const uint4*)&e_s[arowi[rt]*68 + (kp*2 + k2)*16 + q*4];
          #pragma unroll
          for (int ct = 0; ct < 4; ++ct)
            az[rt][ct] = __builtin_amdgcn_mfma_f32_16x16x32_bf16(as_s8(a), as_s8(bb[k2][ct]), az[rt][ct], 0, 0, 0);
        }
  }

  // Z epilogue (consume prefetched alv)
  {
    float wl2v[4], bLv[4];
    #pragma unroll
    for (int ct = 0; ct < 4; ++ct) { wl2v[ct] = wl2_s[colg[ct]]; bLv[ct] = bL_s[colg[ct]]; }
    #pragma unroll
    for (int rt = 0; rt < 2; ++rt) {
      if (rt < nvt) {
        float szr[4] = {0.f,0.f,0.f,0.f};
        #pragma unroll
        for (int ct = 0; ct < 4; ++ct) {
          #pragma unroll
          for (int r = 0; r < 4; ++r) {
            float zv = fmaxf(az[rt][ct][r] + alv[rt][ct][r] + bLv[ct], 0.f);
            szr[r] += zv * wl2v[ct];
          }
        }
        #pragma unroll
        for (int r = 0; r < 4; ++r) {
          szr[r] += __shfl_xor(szr[r], 1);
          szr[r] += __shfl_xor(szr[r], 2);
          szr[r] += __shfl_xor(szr[r], 4);
          szr[r] += __shfl_xor(szr[r], 8);
        }
        if (n == 0) {
          #pragma unroll
          for (int r = 0; r < 4; ++r)
            atomicAdd(&adj[rh2*32 + rt*16 + q*4 + r], szr[r]);
        }
      }
    }
  }

  // Prefetch a_m now (alv dead): latency hides under B2 + M MFMA.
  float amv[2][4][4];
  #pragma unroll
  for (int rt = 0; rt < 2; ++rt)
    if (rt < nvt)
      #pragma unroll
      for (int ct = 0; ct < 4; ++ct)
        #pragma unroll
        for (int r = 0; r < 4; ++r) {
          int lrow = rh2*32 + rt*16 + q*4 + r;
          amv[rt][ct][r] = aMb[(size_t)lrow*128 + colg[ct]];
        }
  __syncthreads();   // B2: adj final

  // ---------- PASS M ----------
  floatx4 am[2][4];
  #pragma unroll
  for (int rt = 0; rt < 2; ++rt)
    #pragma unroll
    for (int ct = 0; ct < 4; ++ct) am[rt][ct] = (floatx4){0.f,0.f,0.f,0.f};
  #pragma unroll
  for (int kp = 0; kp < 2; ++kp) {
    uint4 bb[2][4];
    #pragma unroll
    for (int k2 = 0; k2 < 2; ++k2)
      #pragma unroll
      for (int ct = 0; ct < 4; ++ct)
        bb[k2][ct] = *(const uint4*)(wm + colg[ct]*64 + (kp*2 + k2)*16 + q*4);
    #pragma unroll
    for (int k2 = 0; k2 < 2; ++k2)
      #pragma unroll
      for (int rt = 0; rt < 2; ++rt)
        if (rt < nvt) {
          uint4 a = *(const uint4*)&e_s[arowi[rt]*68 + (kp*2 + k2)*16 + q*4];
          #pragma unroll
          for (int ct = 0; ct < 4; ++ct)
            am[rt][ct] = __builtin_amdgcn_mfma_f32_16x16x32_bf16(as_s8(a), as_s8(bb[k2][ct]), am[rt][ct], 0, 0, 0);
        }
  }

  // M epilogue (consume prefetched amv; per-thread sigmoid)
  {
    float bMv[4];
    #pragma unroll
    for (int ct = 0; ct < 4; ++ct) bMv[ct] = bM_s[colg[ct]];
    float colsum[4] = {0.f,0.f,0.f,0.f};
    #pragma unroll
    for (int rt = 0; rt < 2; ++rt) {
      if (rt < nvt) {
        #pragma unroll
        for (int r = 0; r < 4; ++r) {
          int lrow = rh2*32 + rt*16 + q*4 + r;
          float sc = (lrow < vnl) ? sigf(adj[lrow] + bl2v) : 0.f;
          #pragma unroll
          for (int ct = 0; ct < 4; ++ct) {
            float mv = fmaxf(am[rt][ct][r] + amv[rt][ct][r] + bMv[ct], 0.f) * sc;
            m16[lrow*136 + colg[ct]] = bf16_1(mv);
            colsum[ct] += mv;
          }
        }
      }
    }
    #pragma unroll
    for (int ct = 0; ct < 4; ++ct) {
      float v = colsum[ct];
      v += __shfl_xor(v, 16);
      v += __shfl_xor(v, 32);
      if (lane < 16) atomicAdd(&msum[colg[ct]], v);
    }
  }
  __syncthreads();   // B3
  {
    float* msH = half ? ms1 : ms0;
    if (t < 128) msH[(size_t)(b*128 + j)*128 + t] = msum[t];   // exclusive owner
  }

  // ---------- PASS U ----------
  floatx4 au[2][4];
  #pragma unroll
  for (int rt = 0; rt < 2; ++rt)
    #pragma unroll
    for (int ct = 0; ct < 4; ++ct) au[rt][ct] = (floatx4){0.f,0.f,0.f,0.f};
  #pragma unroll
  for (int kp = 0; kp < 2; ++kp) {
    uint4 bb[2][4];
    #pragma unroll
    for (int k2 = 0; k2 < 2; ++k2)
      #pragma unroll
      for (int ct = 0; ct < 4; ++ct)
        bb[k2][ct] = *(const uint4*)(wue + colg[ct]*64 + (kp*2 + k2)*16 + q*4);
    #pragma unroll
    for (int k2 = 0; k2 < 2; ++k2)
      #pragma unroll
      for (int rt = 0; rt < 2; ++rt)
        if (rt < nvt) {
          uint4 a = *(const uint4*)&e_s[arowi[rt]*68 + (kp*2 + k2)*16 + q*4];
          #pragma unroll
          for (int ct = 0; ct < 4; ++ct)
            au[rt][ct] = __builtin_amdgcn_mfma_f32_16x16x32_bf16(as_s8(a), as_s8(bb[k2][ct]), au[rt][ct], 0, 0, 0);
        }
  }
  #pragma unroll
  for (int kp = 0; kp < 2; ++kp) {
    uint4 bb[2][4];
    #pragma unroll
    for (int k2 = 0; k2 < 2; ++k2)
      #pragma unroll
      for (int ct = 0; ct < 4; ++ct)
        bb[k2][ct] = *(const uint4*)(wum + colg[ct]*64 + (kp*2 + k2)*16 + q*4);
    #pragma unroll
    for (int k2 = 0; k2 < 2; ++k2)
      #pragma unroll
      for (int rt = 0; rt < 2; ++rt)
        if (rt < nvt) {
          uint4 a = *(const uint4*)&m_a[arowi[rt]*68 + (kp*2 + k2)*16 + q*4];
          #pragma unroll
          for (int ct = 0; ct < 4; ++ct)
            au[rt][ct] = __builtin_amdgcn_mfma_f32_16x16x32_bf16(as_s8(a), as_s8(bb[k2][ct]), au[rt][ct], 0, 0, 0);
        }
  }
  __syncthreads();   // B4

  {
    float buv[4];
    #pragma unroll
    for (int ct = 0; ct < 4; ++ct) buv[ct] = bu_s[colg[ct]];
    #pragma unroll
    for (int rt = 0; rt < 2; ++rt)
      if (rt < nvt)
        #pragma unroll
        for (int ct = 0; ct < 4; ++ct)
          #pragma unroll
          for (int r = 0; r < 4; ++r) {
            int lrow = rh2*32 + rt*16 + q*4 + r;
            m16[lrow*136 + colg[ct]] = bf16_1(fmaxf(au[rt][ct][r] + buv[ct], 0.f));
          }
  }
  __syncthreads();   // B5
  #pragma unroll
  for (int it = 0; it < 4; ++it) {
    int f = it*256 + t;
    int lr = f >> 4, c4 = (f & 15) * 4;
    if (row0 + lr < vn)
      *(uint4*)&eblk[(size_t)(row0 + lr)*64 + c4] = *(const uint4*)&m_a[lr*68 + c4];
  }
}

// ---------- MFMA readout, both GEMMs on matrix cores ----------
__global__ __launch_bounds__(256,4) void readout_mfma(
  const unsigned* __restrict__ eg,
  const unsigned* __restrict__ wr1T,
  const unsigned* __restrict__ wr2T,
  const float* __restrict__ br1, const float* __restrict__ br2,
  const int* __restrict__ event_nums, float* __restrict__ out)
{
  __shared__ unsigned f_s[64*132];
  __shared__ int iu_s[64], ju_s[64];
  unsigned short* h16 = (unsigned short*)f_s;

  const int t = threadIdx.x;
  const int b = blockIdx.x / 127, pb = blockIdx.x % 127;
  const int vn = event_nums[b];

  if (t < 64) {
    int p = pb*64 + t;
    float disc = (float)((2*NN-1)*(2*NN-1) - 8*p);
    int iu = (int)(((float)(2*NN-1) - sqrtf(disc)) * 0.5f);
    if (iu < 0) iu = 0; if (iu > NN-2) iu = NN-2;
    while (iu < NN-2 && ((iu+1)*(2*NN-2-iu))/2 <= p) ++iu;
    while (iu > 0 && (iu*(2*NN-1-iu))/2 > p) --iu;
    int ju = p - (iu*(2*NN-1-iu))/2 + iu + 1;
    iu_s[t] = iu; ju_s[t] = ju;
  }
  __syncthreads();

  #pragma unroll
  for (int it = 0; it < 8; ++it) {
    int f4 = it*1024 + t*4;
    int pr = f4 >> 7, w = f4 & 127;
    int side = w >> 6, k2 = w & 63;
    int iu = iu_s[pr], ju = ju_s[pr];
    size_t base = side ? (((size_t)(b*128 + iu))*128 + ju)*64
                       : (((size_t)(b*128 + ju))*128 + iu)*64;
    *(uint4*)&f_s[pr*132 + w] = *(const uint4*)&eg[base + k2];
  }
  __syncthreads();

  const int lane = t & 63, wv = t >> 6;
  const int q = lane >> 4, n = lane & 15;
  int colg[4];
  #pragma unroll
  for (int ct = 0; ct < 4; ++ct) colg[ct] = wv*64 + ct*16 + n;

  floatx4 acc[4][4];
  #pragma unroll
  for (int rt = 0; rt < 4; ++rt)
    #pragma unroll
    for (int ct = 0; ct < 4; ++ct) acc[rt][ct] = (floatx4){0.f,0.f,0.f,0.f};

  #pragma unroll
  for (int kb = 0; kb < 8; ++kb) {
    uint4 bb[4];
    #pragma unroll
    for (int ct = 0; ct < 4; ++ct) bb[ct] = *(const uint4*)(wr1T + (size_t)colg[ct]*128 + kb*16 + q*4);
    #pragma unroll
    for (int rt = 0; rt < 4; ++rt) {
      uint4 a = *(const uint4*)&f_s[(rt*16 + n)*132 + kb*16 + q*4];
      #pragma unroll
      for (int ct = 0; ct < 4; ++ct)
        acc[rt][ct] = __builtin_amdgcn_mfma_f32_16x16x32_bf16(as_s8(a), as_s8(bb[ct]), acc[rt][ct], 0, 0, 0);
    }
  }
  __syncthreads();

  {
    float brv[4];
    #pragma unroll
    for (int ct = 0; ct < 4; ++ct) brv[ct] = br1[colg[ct]];
    #pragma unroll
    for (int rt = 0; rt < 4; ++rt)
      #pragma unroll
      for (int ct = 0; ct < 4; ++ct)
        #pragma unroll
        for (int r = 0; r < 4; ++r) {
          int pr = rt*16 + q*4 + r;
          h16[pr*264 + colg[ct]] = bf16_1(fmaxf(acc[rt][ct][r] + brv[ct], 0.f));
        }
  }
  __syncthreads();

  floatx4 acc2 = (floatx4){0.f,0.f,0.f,0.f};
  #pragma unroll
  for (int kb = 0; kb < 8; ++kb) {
    uint4 bb = *(const uint4*)(wr2T + n*128 + kb*16 + q*4);
    uint4 a  = *(const uint4*)&f_s[(wv*16 + n)*132 + kb*16 + q*4];
    acc2 = __builtin_amdgcn_mfma_f32_16x16x32_bf16(as_s8(a), as_s8(bb), acc2, 0, 0, 0);
  }

  if (n < 10) {
    float bias = br2[n];
    #pragma unroll
    for (int r = 0; r < 4; ++r) {
      int pr = wv*16 + q*4 + r;
      int iu = iu_s[pr], ju = ju_s[pr];
      if (ju < vn) {
        int idx = iu*vn - (iu*(iu+1))/2 + (ju - iu - 1);
        out[(((size_t)b*5 + (n>>1))*PP + idx)*2 + (n&1)] = acc2[r] + bias;
      }
    }
  }
}

extern "C" void kernel_launch(void* const* d_in, const int* in_sizes, int n_in,
                              void* d_out, int out_size, void* d_ws, size_t ws_size,
                              hipStream_t stream) {
  const int*   edge_ids      = (const int*)d_in[0];
  const float* node_features = (const float*)d_in[1];
  const int*   event_nums    = (const int*)d_in[3];
  const float* emb  = (const float*)d_in[4];
  const float* Wl_e = (const float*)d_in[5];
  const float* Wl_w = (const float*)d_in[6];
  const float* Wl_v = (const float*)d_in[7];
  const float* bl1  = (const float*)d_in[8];
  const float* wl2  = (const float*)d_in[9];
  const float* bl2  = (const float*)d_in[10];
  const float* Wm_w = (const float*)d_in[11];
  const float* Wm_v = (const float*)d_in[12];
  const float* Wm_e = (const float*)d_in[13];
  const float* bm   = (const float*)d_in[14];
  const float* Wu_e = (const float*)d_in[15];
  const float* Wu_m = (const float*)d_in[16];
  const float* bu   = (const float*)d_in[17];
  const float* W_ih = (const float*)d_in[18];
  const float* W_hh = (const float*)d_in[19];
  const float* b_ih = (const float*)d_in[20];
  const float* b_hh = (const float*)d_in[21];
  const float* Wr1  = (const float*)d_in[22];
  const float* br1  = (const float*)d_in[23];
  const float* Wr2  = (const float*)d_in[24];
  const float* br2  = (const float*)d_in[25];

  const size_t SZ_E = (size_t)134217728;       // B*N*N*64 u32
  const size_t SZ_S = (size_t)2097152;         // B*N*128 f32
  const size_t SZ_W = (size_t)131072;          // 32768 u32
  const size_t SZ_W2 = (size_t)8192;           // 2048 u32
  const size_t SZ_TAB = (size_t)2048;          // 512 f32 each
  const size_t SZ_WIH = (size_t)98304;         // 24576 u32 (384 cols x 64)
  const size_t SZ_W4  = (size_t)131072;        // 32768 u32 (512 cols x 64)
  const size_t need = SZ_E + 7*SZ_S + 2*SZ_W + SZ_W2 + 3*SZ_TAB + 2*SZ_WIH + SZ_W4;

  hipMemsetAsync(d_out, 0, (size_t)out_size * sizeof(float), stream);
  if (ws_size < need) return;

  char* w = (char*)d_ws;
  unsigned* eg   = (unsigned*)w; w += SZ_E;
  float* h_ws = (float*)w; w += SZ_S;
  float* a_l  = (float*)w; w += SZ_S;
  float* b_l  = (float*)w; w += SZ_S;
  float* a_m  = (float*)w; w += SZ_S;
  float* b_m  = (float*)w; w += SZ_S;
  float* ms0  = (float*)w; w += SZ_S;
  float* ms1  = (float*)w; w += SZ_S;
  unsigned* wT   = (unsigned*)w; w += SZ_W;
  unsigned* wr1T = (unsigned*)w; w += SZ_W;
  unsigned* wr2T = (unsigned*)w; w += SZ_W2;
  float* embZ = (float*)w; w += SZ_TAB;
  float* embM = (float*)w; w += SZ_TAB;
  float* embU = (float*)w; w += SZ_TAB;
  unsigned* wihT = (unsigned*)w; w += SZ_WIH;
  unsigned* whhT = (unsigned*)w; w += SZ_WIH;
  unsigned* w4T  = (unsigned*)w; w += SZ_W4;

  hipLaunchKernelGGL(conv_w_kernel, dim3(576), dim3(256), 0, stream,
      Wl_e, Wm_e, Wu_e, Wu_m, Wr1, Wr2, emb,
      W_ih, W_hh, Wl_w, Wl_v, Wm_w, Wm_v,
      wT, wr1T, wr2T, embZ, embM, embU, wihT, whhT, w4T);

  hipLaunchKernelGGL(gru_mfma, dim3(256), dim3(256), 0, stream,
      0, ms0, ms1, node_features, h_ws, wihT, whhT, w4T,
      b_ih, b_hh, event_nums, a_l, b_l, a_m, b_m);

  for (int r = 0; r < 3; ++r) {
    if (r == 0) {
      hipLaunchKernelGGL(edge_round_first, dim3(8192), dim3(256), 0, stream,
          eg, wT, edge_ids, embZ, embM, embU,
          a_l, b_l, a_m, b_m, bl1, wl2, bl2, bm, bu, event_nums, ms0, ms1);
    } else {
      hipLaunchKernelGGL(edge_round_rest, dim3(8192), dim3(256), 0, stream,
          eg, wT, a_l, b_l, a_m, b_m, bl1, wl2, bl2, bm, bu, event_nums, ms0, ms1);
    }
    if (r < 2) {
      const float* hin = (r == 0) ? node_features : h_ws;
      hipLaunchKernelGGL(gru_mfma, dim3(256), dim3(256), 0, stream,
          1, ms0, ms1, hin, h_ws, wihT, whhT, w4T,
          b_ih, b_hh, event_nums, a_l, b_l, a_m, b_m);
    }
  }

  hipLaunchKernelGGL(readout_mfma, dim3(BB*127), dim3(256), 0, stream,
      eg, wr1T, wr2T, br1, br2, event_nums, (float*)d_out);
}

// Round 14
// 601.211 us; speedup vs baseline: 1.8647x; 1.0076x over previous
//
#include <hip/hip_runtime.h>
#include <cstddef>

// Problem constants
#define BB 32
#define NN 128
#define PP 8128

typedef __attribute__((ext_vector_type(8))) short short8;
typedef __attribute__((ext_vector_type(4))) float floatx4;

union U4S8 { uint4 u; short8 s; };
__device__ __forceinline__ short8 as_s8(uint4 v){ U4S8 x; x.u = v; return x.s; }

// ---------- bf16 helpers ----------
__device__ __forceinline__ unsigned pack_bf16(float a, float b){
  union{float f;unsigned u;}xa,xb; xa.f=a; xb.f=b;
  unsigned ua=xa.u, ub=xb.u;
  ua = (ua + 0x7fffu + ((ua>>16)&1u)) >> 16;
  ub = (ub + 0x7fffu + ((ub>>16)&1u)) >> 16;
  return (ua & 0xffffu) | (ub << 16);
}
__device__ __forceinline__ unsigned short bf16_1(float a){
  union{float f;unsigned u;}x; x.f=a;
  return (unsigned short)((x.u + 0x7fffu + ((x.u>>16)&1u)) >> 16);
}
__device__ __forceinline__ float sigf(float x){ return 1.f/(1.f + __expf(-x)); }

// Bijective block remap (kept from R5).
__device__ __forceinline__ void decode_blk(int gid, int& b, int& j, int& half){
  b    = ((gid>>11)&3)*8 + ((gid>>5)&7);
  j    = ((gid>>9)&3)*32 + (gid&31);
  half = (gid>>8)&1;
}

// ---------- weight conversion + round-0 tables (+ GRU/proj weights) ----------
__global__ __launch_bounds__(256,4) void conv_w_kernel(
  const float* __restrict__ Wl_e, const float* __restrict__ Wm_e,
  const float* __restrict__ Wu_e, const float* __restrict__ Wu_m,
  const float* __restrict__ Wr1, const float* __restrict__ Wr2,
  const float* __restrict__ emb,
  const float* __restrict__ W_ih, const float* __restrict__ W_hh,
  const float* __restrict__ Wl_w, const float* __restrict__ Wl_v,
  const float* __restrict__ Wm_w, const float* __restrict__ Wm_v,
  unsigned* __restrict__ wT, unsigned* __restrict__ wr1T,
  unsigned* __restrict__ wr2T,
  float* __restrict__ embZ, float* __restrict__ embM, float* __restrict__ embU,
  unsigned* __restrict__ wihT, unsigned* __restrict__ whhT,
  unsigned* __restrict__ w4T)
{
  int tid = blockIdx.x*256 + threadIdx.x;
  if (tid < 65536) {
    if (tid < 2048) {   // Wr2 [256][10] -> B-frag layout [16 cols][128 k2], zero-padded
      int c = tid >> 7, k2 = tid & 127;
      unsigned v = 0;
      if (c < 10) v = pack_bf16(Wr2[(2*k2)*10 + c], Wr2[(2*k2+1)*10 + c]);
      wr2T[c*128 + k2] = v;
    }
    if (tid >= 4096 && tid < 5632) {   // round-0 tables: emb(4x128) @ W(128x128), f32
      int idx = tid - 4096;            // 0..1535
      int tb = idx >> 9;               // 0..2
      int r  = idx & 511;
      int id = r >> 7, c = r & 127;
      const float* W = (tb==0) ? Wl_e : (tb==1) ? Wm_e : Wu_e;
      float s = 0.f;
      #pragma unroll 4
      for (int k = 0; k < 128; ++k) s += emb[id*128 + k] * W[(size_t)k*128 + c];
      float* T = (tb==0) ? embZ : (tb==1) ? embM : embU;
      T[r] = s;
    }
    if (tid < 32768) {
      int mat = tid >> 13, r = tid & 8191;
      int k2 = r >> 7, c = r & 127;
      const float* W = (mat==0) ? Wl_e : (mat==1) ? Wm_e : (mat==2) ? Wu_e : Wu_m;
      wT[mat*8192 + c*64 + k2] = pack_bf16(W[(2*k2)*128 + c], W[(2*k2+1)*128 + c]);
    } else {
      int r = tid - 32768;
      int k2 = r >> 8, c = r & 255;
      wr1T[(size_t)c*128 + k2] = pack_bf16(Wr1[(2*k2)*256 + c], Wr1[(2*k2+1)*256 + c]);
    }
  } else {
    int t2 = tid - 65536;              // 0..81919
    if (t2 < 24576) {                  // W_ih [128][384] -> wihT[c*64+k2]
      int c = t2 >> 6, k2 = t2 & 63;
      wihT[c*64 + k2] = pack_bf16(W_ih[(size_t)(2*k2)*384 + c], W_ih[(size_t)(2*k2+1)*384 + c]);
    } else if (t2 < 49152) {           // W_hh [128][384]
      int r = t2 - 24576;
      int c = r >> 6, k2 = r & 63;
      whhT[c*64 + k2] = pack_bf16(W_hh[(size_t)(2*k2)*384 + c], W_hh[(size_t)(2*k2+1)*384 + c]);
    } else if (t2 < 81920) {           // {Wl_w,Wl_v,Wm_w,Wm_v} [128][128]
      int r = t2 - 49152;
      int m = r >> 13, rr = r & 8191;
      int c = rr >> 6, k2 = rr & 63;
      const float* W = (m==0) ? Wl_w : (m==1) ? Wl_v : (m==2) ? Wm_w : Wm_v;
      w4T[m*8192 + c*64 + k2] = pack_bf16(W[(2*k2)*128 + c], W[(2*k2+1)*128 + c]);
    }
  }
}

// ---------- MFMA GRU + node projections ----------
__global__ __launch_bounds__(256,4) void gru_mfma(
  int do_gru,
  const float* __restrict__ ms0, const float* __restrict__ ms1,
  const float* __restrict__ h_in, float* __restrict__ h_out,
  const unsigned* __restrict__ wihT, const unsigned* __restrict__ whhT,
  const unsigned* __restrict__ w4T,
  const float* __restrict__ b_ih, const float* __restrict__ b_hh,
  const int* __restrict__ event_nums,
  float* __restrict__ a_l, float* __restrict__ b_l,
  float* __restrict__ a_m, float* __restrict__ b_m)
{
  __shared__ unsigned msT[16*68], hT[16*68], hnT[16*68];
  unsigned short* hn16 = (unsigned short*)hnT;

  const int t = threadIdx.x;
  const int bg = blockIdx.x;
  const int b = bg >> 3, row0 = (bg & 7) * 16;
  const int vn = event_nums[b];
  const int lane = t & 63, wv = t >> 6;
  const int q = lane >> 4, n = lane & 15;

  // stage inputs to bf16 LDS A-tiles (16 rows x 64 u32)
  #pragma unroll
  for (int i = 0; i < 4; ++i) {
    int idx = i*256 + t;               // 0..1023
    int r = idx >> 6, c2 = idx & 63;
    size_t base = ((size_t)(b*128 + row0 + r))*128 + 2*c2;
    if (do_gru) {
      float m0 = ms0[base], m1 = ms0[base + 1];
      if (vn > 64) { m0 += ms1[base]; m1 += ms1[base + 1]; }
      msT[r*68 + c2] = pack_bf16(m0, m1);
      hT[r*68 + c2]  = pack_bf16(h_in[base], h_in[base + 1]);
    } else {
      hnT[r*68 + c2] = pack_bf16(h_in[base], h_in[base + 1]);
    }
  }
  __syncthreads();

  if (do_gru) {
    #pragma unroll
    for (int cc = 0; cc < 2; ++cc) {
      int c = (wv*2 + cc)*16 + n;      // absolute gate/h column
      floatx4 air = (floatx4){0.f,0.f,0.f,0.f};
      floatx4 aiz = (floatx4){0.f,0.f,0.f,0.f};
      floatx4 ain = (floatx4){0.f,0.f,0.f,0.f};
      floatx4 ahr = (floatx4){0.f,0.f,0.f,0.f};
      floatx4 ahz = (floatx4){0.f,0.f,0.f,0.f};
      floatx4 ahn = (floatx4){0.f,0.f,0.f,0.f};
      #pragma unroll
      for (int kb = 0; kb < 4; ++kb) {
        uint4 ma = *(const uint4*)&msT[n*68 + kb*16 + q*4];
        uint4 ha = *(const uint4*)&hT[n*68 + kb*16 + q*4];
        uint4 b0 = *(const uint4*)(wihT + (size_t)c*64        + kb*16 + q*4);
        uint4 b1 = *(const uint4*)(wihT + (size_t)(128+c)*64  + kb*16 + q*4);
        uint4 b2 = *(const uint4*)(wihT + (size_t)(256+c)*64  + kb*16 + q*4);
        uint4 h0 = *(const uint4*)(whhT + (size_t)c*64        + kb*16 + q*4);
        uint4 h1 = *(const uint4*)(whhT + (size_t)(128+c)*64  + kb*16 + q*4);
        uint4 h2 = *(const uint4*)(whhT + (size_t)(256+c)*64  + kb*16 + q*4);
        air = __builtin_amdgcn_mfma_f32_16x16x32_bf16(as_s8(ma), as_s8(b0), air, 0, 0, 0);
        aiz = __builtin_amdgcn_mfma_f32_16x16x32_bf16(as_s8(ma), as_s8(b1), aiz, 0, 0, 0);
        ain = __builtin_amdgcn_mfma_f32_16x16x32_bf16(as_s8(ma), as_s8(b2), ain, 0, 0, 0);
        ahr = __builtin_amdgcn_mfma_f32_16x16x32_bf16(as_s8(ha), as_s8(h0), ahr, 0, 0, 0);
        ahz = __builtin_amdgcn_mfma_f32_16x16x32_bf16(as_s8(ha), as_s8(h1), ahz, 0, 0, 0);
        ahn = __builtin_amdgcn_mfma_f32_16x16x32_bf16(as_s8(ha), as_s8(h2), ahn, 0, 0, 0);
      }
      float bi0 = b_ih[c], bi1 = b_ih[128 + c], bi2 = b_ih[256 + c];
      float bh0 = b_hh[c], bh1 = b_hh[128 + c], bh2 = b_hh[256 + c];
      #pragma unroll
      for (int r = 0; r < 4; ++r) {
        int node = row0 + q*4 + r;
        size_t gidx = ((size_t)(b*128 + node))*128 + c;
        float hold = h_in[gidx];
        float rr = sigf(air[r] + bi0 + ahr[r] + bh0);
        float zg = sigf(aiz[r] + bi1 + ahz[r] + bh1);
        float nn = tanhf(ain[r] + bi2 + rr*(ahn[r] + bh2));
        float hv = (node < vn) ? (1.f - zg)*nn + zg*hold : hold;
        h_out[gidx] = hv;
        hn16[(q*4 + r)*136 + c] = bf16_1(hv);
      }
    }
    __syncthreads();   // hnT final
  }

  // phase 2: projections hnT @ w4T. Wave wv owns matrix wv (128 cols = 8 col-tiles).
  float* Out = (wv == 0) ? a_l : (wv == 1) ? b_l : (wv == 2) ? a_m : b_m;
  #pragma unroll
  for (int g = 0; g < 2; ++g) {
    floatx4 acc[4];
    #pragma unroll
    for (int c4 = 0; c4 < 4; ++c4) acc[c4] = (floatx4){0.f,0.f,0.f,0.f};
    #pragma unroll
    for (int kb = 0; kb < 4; ++kb) {
      uint4 a = *(const uint4*)&hnT[n*68 + kb*16 + q*4];
      #pragma unroll
      for (int c4 = 0; c4 < 4; ++c4) {
        int ct = wv*8 + g*4 + c4;       // global 16-col tile in [0,32)
        uint4 bb = *(const uint4*)(w4T + (size_t)(ct*16 + n)*64 + kb*16 + q*4);
        acc[c4] = __builtin_amdgcn_mfma_f32_16x16x32_bf16(as_s8(a), as_s8(bb), acc[c4], 0, 0, 0);
      }
    }
    #pragma unroll
    for (int c4 = 0; c4 < 4; ++c4) {
      int c = (g*4 + c4)*16 + n;        // column within this wave's matrix
      #pragma unroll
      for (int r = 0; r < 4; ++r) {
        int node = row0 + q*4 + r;
        Out[((size_t)(b*128 + node))*128 + c] = acc[c4][r];
      }
    }
  }
}

// ---------- edge round 0: table-driven (no E GEMMs), only M@Wu_m on MFMA ----------
__global__ __launch_bounds__(256,4) void edge_round_first(
  unsigned* __restrict__ eg,
  const unsigned* __restrict__ wT,     // need wum = wT+24576
  const int* __restrict__ ids,
  const float* __restrict__ embZ, const float* __restrict__ embM,
  const float* __restrict__ embU,
  const float* __restrict__ a_l, const float* __restrict__ b_l,
  const float* __restrict__ a_m, const float* __restrict__ b_m,
  const float* __restrict__ bl1, const float* __restrict__ wl2,
  const float* __restrict__ bl2, const float* __restrict__ bm,
  const float* __restrict__ bu,
  const int* __restrict__ event_nums,
  float* __restrict__ ms0, float* __restrict__ ms1)
{
  __shared__ unsigned m_a[64*68];
  __shared__ float adj[64], msum[128];
  __shared__ float bL_s[128], bM_s[128], bu_s[128], wl2_s[128];
  __shared__ float tabZ[512], tabM[512], tabU[512];
  __shared__ int id_s[64];
  unsigned short* m16 = (unsigned short*)m_a;

  const int t = threadIdx.x;
  int b, j, half;
  decode_blk(blockIdx.x, b, j, half);
  const int vn = event_nums[b];
  const int row0 = half*64;
  int vnl = vn - row0; vnl = vnl < 0 ? 0 : (vnl > 64 ? 64 : vnl);
  if (j >= vn || vnl == 0) return;

  unsigned* eblk = eg + (size_t)(b*128 + j) * 8192;
  const float bl2v = bl2[0];

  if (t < 128) {
    bL_s[t] = b_l[(size_t)(b*128 + j)*128 + t] + bl1[t];
    bM_s[t] = b_m[(size_t)(b*128 + j)*128 + t] + bm[t];
    bu_s[t] = bu[t];
    wl2_s[t] = wl2[t];
    msum[t] = 0.f;
  }
  if (t < 64) {
    adj[t] = 0.f;
    id_s[t] = ids[((size_t)(b*128 + row0 + t))*128 + j];
  }
  for (int i = t; i < 512; i += 256) {
    tabZ[i] = embZ[i]; tabM[i] = embM[i]; tabU[i] = embU[i];
  }

  const int lane = t & 63, wv = t >> 6;
  const int q = lane >> 4, n = lane & 15;
  const int rh2 = wv >> 1, ch = wv & 1;

  int nvt = (vnl - rh2*32 + 15) >> 4;
  nvt = nvt < 0 ? 0 : (nvt > 2 ? 2 : nvt);

  const unsigned* wum = wT + 24576;
  int colg[4];
  #pragma unroll
  for (int ct = 0; ct < 4; ++ct) colg[ct] = ch*64 + ct*16 + n;
  int arowi[2];
  #pragma unroll
  for (int rt = 0; rt < 2; ++rt) arowi[rt] = rh2*32 + rt*16 + n;

  // Prefetch a_l / a_m into registers (hide L2/L3 latency under barrier + tables)
  const float* aLb = a_l + (size_t)(b*128 + row0)*128;
  const float* aMb = a_m + (size_t)(b*128 + row0)*128;
  float alv[2][4][4], amv[2][4][4];
  #pragma unroll
  for (int rt = 0; rt < 2; ++rt)
    if (rt < nvt)
      #pragma unroll
      for (int ct = 0; ct < 4; ++ct)
        #pragma unroll
        for (int r = 0; r < 4; ++r) {
          int lrow = rh2*32 + rt*16 + q*4 + r;
          alv[rt][ct][r] = aLb[(size_t)lrow*128 + colg[ct]];
          amv[rt][ct][r] = aMb[(size_t)lrow*128 + colg[ct]];
        }
  __syncthreads();   // B1

  // Z epilogue from tables
  {
    float wl2v[4], bLv[4];
    #pragma unroll
    for (int ct = 0; ct < 4; ++ct) { wl2v[ct] = wl2_s[colg[ct]]; bLv[ct] = bL_s[colg[ct]]; }
    #pragma unroll
    for (int rt = 0; rt < 2; ++rt) {
      if (rt < nvt) {
        float szr[4] = {0.f,0.f,0.f,0.f};
        #pragma unroll
        for (int ct = 0; ct < 4; ++ct) {
          #pragma unroll
          for (int r = 0; r < 4; ++r) {
            int lrow = rh2*32 + rt*16 + q*4 + r;
            float zv = fmaxf(tabZ[id_s[lrow]*128 + colg[ct]] + alv[rt][ct][r] + bLv[ct], 0.f);
            szr[r] += zv * wl2v[ct];
          }
        }
        #pragma unroll
        for (int r = 0; r < 4; ++r) {
          szr[r] += __shfl_xor(szr[r], 1);
          szr[r] += __shfl_xor(szr[r], 2);
          szr[r] += __shfl_xor(szr[r], 4);
          szr[r] += __shfl_xor(szr[r], 8);
        }
        if (n == 0) {
          #pragma unroll
          for (int r = 0; r < 4; ++r)
            atomicAdd(&adj[rh2*32 + rt*16 + q*4 + r], szr[r]);
        }
      }
    }
  }
  __syncthreads();   // B2: adj final

  // M epilogue from tables -> m16, msum (per-thread sigmoid, no svec)
  {
    float bMv[4];
    #pragma unroll
    for (int ct = 0; ct < 4; ++ct) bMv[ct] = bM_s[colg[ct]];
    float colsum[4] = {0.f,0.f,0.f,0.f};
    #pragma unroll
    for (int rt = 0; rt < 2; ++rt) {
      if (rt < nvt) {
        #pragma unroll
        for (int r = 0; r < 4; ++r) {
          int lrow = rh2*32 + rt*16 + q*4 + r;
          float sc = (lrow < vnl) ? sigf(adj[lrow] + bl2v) : 0.f;
          #pragma unroll
          for (int ct = 0; ct < 4; ++ct) {
            float mv = fmaxf(tabM[id_s[lrow]*128 + colg[ct]] + amv[rt][ct][r] + bMv[ct], 0.f) * sc;
            m16[lrow*136 + colg[ct]] = bf16_1(mv);
            colsum[ct] += mv;
          }
        }
      }
    }
    #pragma unroll
    for (int ct = 0; ct < 4; ++ct) {
      float v = colsum[ct];
      v += __shfl_xor(v, 16);
      v += __shfl_xor(v, 32);
      if (lane < 16) atomicAdd(&msum[colg[ct]], v);
    }
  }
  __syncthreads();   // B3
  {
    float* msH = half ? ms1 : ms0;
    if (t < 128) msH[(size_t)(b*128 + j)*128 + t] = msum[t];   // exclusive owner
  }

  // U = tabU gather + M@Wu_m
  floatx4 au[2][4];
  #pragma unroll
  for (int rt = 0; rt < 2; ++rt)
    #pragma unroll
    for (int ct = 0; ct < 4; ++ct) {
      au[rt][ct] = (floatx4){0.f,0.f,0.f,0.f};
      if (rt < nvt)
        #pragma unroll
        for (int r = 0; r < 4; ++r) {
          int lrow = rh2*32 + rt*16 + q*4 + r;
          au[rt][ct][r] = tabU[id_s[lrow]*128 + colg[ct]];
        }
    }
  #pragma unroll
  for (int kb = 0; kb < 4; ++kb) {
    uint4 bb[4];
    #pragma unroll
    for (int ct = 0; ct < 4; ++ct) bb[ct] = *(const uint4*)(wum + colg[ct]*64 + kb*16 + q*4);
    #pragma unroll
    for (int rt = 0; rt < 2; ++rt)
      if (rt < nvt) {
        uint4 a = *(const uint4*)&m_a[arowi[rt]*68 + kb*16 + q*4];
        #pragma unroll
        for (int ct = 0; ct < 4; ++ct)
          au[rt][ct] = __builtin_amdgcn_mfma_f32_16x16x32_bf16(as_s8(a), as_s8(bb[ct]), au[rt][ct], 0, 0, 0);
      }
  }
  __syncthreads();   // B4: all waves done reading m_a

  // U epilogue -> m16 (own 32-row x 64-col region), then per-wave writeback.
  // Same-wave LDS write->read: no barrier needed (B5 deleted).
  {
    float buv[4];
    #pragma unroll
    for (int ct = 0; ct < 4; ++ct) buv[ct] = bu_s[colg[ct]];
    #pragma unroll
    for (int rt = 0; rt < 2; ++rt)
      if (rt < nvt)
        #pragma unroll
        for (int ct = 0; ct < 4; ++ct)
          #pragma unroll
          for (int r = 0; r < 4; ++r) {
            int lrow = rh2*32 + rt*16 + q*4 + r;
            m16[lrow*136 + colg[ct]] = bf16_1(fmaxf(au[rt][ct][r] + buv[ct], 0.f));
          }
  }
  {
    const int c4 = ch*32 + (lane & 7) * 4;
    #pragma unroll
    for (int it = 0; it < 4; ++it) {
      int lr = rh2*32 + it*8 + (lane >> 3);
      if (row0 + lr < vn)
        *(uint4*)&eblk[(size_t)(row0 + lr)*64 + c4] = *(const uint4*)&m_a[lr*68 + c4];
    }
  }
}

// ---------- edge rounds >=1: 3 MFMA passes, LDS-staged E, 64-row half-blocks ----------
__global__ __launch_bounds__(256,4) void edge_round_rest(
  unsigned* __restrict__ eg,
  const unsigned* __restrict__ wT,
  const float* __restrict__ a_l, const float* __restrict__ b_l,
  const float* __restrict__ a_m, const float* __restrict__ b_m,
  const float* __restrict__ bl1, const float* __restrict__ wl2,
  const float* __restrict__ bl2, const float* __restrict__ bm,
  const float* __restrict__ bu,
  const int* __restrict__ event_nums,
  float* __restrict__ ms0, float* __restrict__ ms1)
{
  __shared__ unsigned e_s[64*68];
  __shared__ unsigned m_a[64*68];
  __shared__ float adj[64], msum[128];
  __shared__ float bL_s[128], bM_s[128], bu_s[128], wl2_s[128];
  unsigned short* m16 = (unsigned short*)m_a;

  const int t = threadIdx.x;
  int b, j, half;
  decode_blk(blockIdx.x, b, j, half);
  const int vn = event_nums[b];
  const int row0 = half*64;
  int vnl = vn - row0; vnl = vnl < 0 ? 0 : (vnl > 64 ? 64 : vnl);
  if (j >= vn || vnl == 0) return;

  unsigned* eblk = eg + (size_t)(b*128 + j) * 8192;
  const float bl2v = bl2[0];

  if (t < 128) {
    bL_s[t] = b_l[(size_t)(b*128 + j)*128 + t] + bl1[t];
    bM_s[t] = b_m[(size_t)(b*128 + j)*128 + t] + bm[t];
    bu_s[t] = bu[t];
    wl2_s[t] = wl2[t];
    msum[t] = 0.f;
  }
  if (t < 64) adj[t] = 0.f;
  {
    const int vnc16 = (vnl + 15) & ~15;
    const int srow = t >> 4, c4 = (t & 15) * 4;
    #pragma unroll
    for (int it = 0; it < 4; ++it) {
      int lr = it*16 + srow;
      if (lr < vnc16)
        *(uint4*)&e_s[lr*68 + c4] = *(const uint4*)&eblk[(size_t)(row0 + lr)*64 + c4];
    }
  }

  const int lane = t & 63, wv = t >> 6;
  const int q = lane >> 4, n = lane & 15;
  const int rh2 = wv >> 1, ch = wv & 1;

  int nvt = (vnl - rh2*32 + 15) >> 4;
  nvt = nvt < 0 ? 0 : (nvt > 2 ? 2 : nvt);

  const unsigned* wz  = wT;
  const unsigned* wm  = wT + 8192;
  const unsigned* wue = wT + 16384;
  const unsigned* wum = wT + 24576;

  int colg[4];
  #pragma unroll
  for (int ct = 0; ct < 4; ++ct) colg[ct] = ch*64 + ct*16 + n;
  int arowi[2];
  #pragma unroll
  for (int rt = 0; rt < 2; ++rt) arowi[rt] = rh2*32 + rt*16 + n;

  // Prefetch a_l into registers pre-B1: latency hides under staging + Z MFMA.
  const float* aLb = a_l + (size_t)(b*128 + row0)*128;
  const float* aMb = a_m + (size_t)(b*128 + row0)*128;
  float alv[2][4][4];
  #pragma unroll
  for (int rt = 0; rt < 2; ++rt)
    if (rt < nvt)
      #pragma unroll
      for (int ct = 0; ct < 4; ++ct)
        #pragma unroll
        for (int r = 0; r < 4; ++r) {
          int lrow = rh2*32 + rt*16 + q*4 + r;
          alv[rt][ct][r] = aLb[(size_t)lrow*128 + colg[ct]];
        }
  __syncthreads();   // B1

  // ---------- PASS Z ----------
  floatx4 az[2][4];
  #pragma unroll
  for (int rt = 0; rt < 2; ++rt)
    #pragma unroll
    for (int ct = 0; ct < 4; ++ct) az[rt][ct] = (floatx4){0.f,0.f,0.f,0.f};
  #pragma unroll
  for (int kp = 0; kp < 2; ++kp) {   // two kb per iteration: 8 B-loads in flight
    uint4 bb[2][4];
    #pragma unroll
    for (int k2 = 0; k2 < 2; ++k2)
      #pragma unroll
      for (int ct = 0; ct < 4; ++ct)
        bb[k2][ct] = *(const uint4*)(wz + colg[ct]*64 + (kp*2 + k2)*16 + q*4);
    #pragma unroll
    for (int k2 = 0; k2 < 2; ++k2)
      #pragma unroll
      for (int rt = 0; rt < 2; ++rt)
        if (rt < nvt) {
          uint4 a = *(const uint4*)&e_s[arowi[rt]*68 + (kp*2 + k2)*16 + q*4];
          #pragma unroll
          for (int ct = 0; ct < 4; ++ct)
            az[rt][ct] = __builtin_amdgcn_mfma_f32_16x16x32_bf16(as_s8(a), as_s8(bb[k2][ct]), az[rt][ct], 0, 0, 0);
        }
  }

  // Z epilogue (consume prefetched alv)
  {
    float wl2v[4], bLv[4];
    #pragma unroll
    for (int ct = 0; ct < 4; ++ct) { wl2v[ct] = wl2_s[colg[ct]]; bLv[ct] = bL_s[colg[ct]]; }
    #pragma unroll
    for (int rt = 0; rt < 2; ++rt) {
      if (rt < nvt) {
        float szr[4] = {0.f,0.f,0.f,0.f};
        #pragma unroll
        for (int ct = 0; ct < 4; ++ct) {
          #pragma unroll
          for (int r = 0; r < 4; ++r) {
            float zv = fmaxf(az[rt][ct][r] + alv[rt][ct][r] + bLv[ct], 0.f);
            szr[r] += zv * wl2v[ct];
          }
        }
        #pragma unroll
        for (int r = 0; r < 4; ++r) {
          szr[r] += __shfl_xor(szr[r], 1);
          szr[r] += __shfl_xor(szr[r], 2);
          szr[r] += __shfl_xor(szr[r], 4);
          szr[r] += __shfl_xor(szr[r], 8);
        }
        if (n == 0) {
          #pragma unroll
          for (int r = 0; r < 4; ++r)
            atomicAdd(&adj[rh2*32 + rt*16 + q*4 + r], szr[r]);
        }
      }
    }
  }

  // Prefetch a_m now (alv dead): latency hides under B2 + M MFMA.
  float amv[2][4][4];
  #pragma unroll
  for (int rt = 0; rt < 2; ++rt)
    if (rt < nvt)
      #pragma unroll
      for (int ct = 0; ct < 4; ++ct)
        #pragma unroll
        for (int r = 0; r < 4; ++r) {
          int lrow = rh2*32 + rt*16 + q*4 + r;
          amv[rt][ct][r] = aMb[(size_t)lrow*128 + colg[ct]];
        }
  __syncthreads();   // B2: adj final

  // ---------- PASS M ----------
  floatx4 am[2][4];
  #pragma unroll
  for (int rt = 0; rt < 2; ++rt)
    #pragma unroll
    for (int ct = 0; ct < 4; ++ct) am[rt][ct] = (floatx4){0.f,0.f,0.f,0.f};
  #pragma unroll
  for (int kp = 0; kp < 2; ++kp) {
    uint4 bb[2][4];
    #pragma unroll
    for (int k2 = 0; k2 < 2; ++k2)
      #pragma unroll
      for (int ct = 0; ct < 4; ++ct)
        bb[k2][ct] = *(const uint4*)(wm + colg[ct]*64 + (kp*2 + k2)*16 + q*4);
    #pragma unroll
    for (int k2 = 0; k2 < 2; ++k2)
      #pragma unroll
      for (int rt = 0; rt < 2; ++rt)
        if (rt < nvt) {
          uint4 a = *(const uint4*)&e_s[arowi[rt]*68 + (kp*2 + k2)*16 + q*4];
          #pragma unroll
          for (int ct = 0; ct < 4; ++ct)
            am[rt][ct] = __builtin_amdgcn_mfma_f32_16x16x32_bf16(as_s8(a), as_s8(bb[k2][ct]), am[rt][ct], 0, 0, 0);
        }
  }

  // M epilogue (consume prefetched amv; per-thread sigmoid)
  {
    float bMv[4];
    #pragma unroll
    for (int ct = 0; ct < 4; ++ct) bMv[ct] = bM_s[colg[ct]];
    float colsum[4] = {0.f,0.f,0.f,0.f};
    #pragma unroll
    for (int rt = 0; rt < 2; ++rt) {
      if (rt < nvt) {
        #pragma unroll
        for (int r = 0; r < 4; ++r) {
          int lrow = rh2*32 + rt*16 + q*4 + r;
          float sc = (lrow < vnl) ? sigf(adj[lrow] + bl2v) : 0.f;
          #pragma unroll
          for (int ct = 0; ct < 4; ++ct) {
            float mv = fmaxf(am[rt][ct][r] + amv[rt][ct][r] + bMv[ct], 0.f) * sc;
            m16[lrow*136 + colg[ct]] = bf16_1(mv);
            colsum[ct] += mv;
          }
        }
      }
    }
    #pragma unroll
    for (int ct = 0; ct < 4; ++ct) {
      float v = colsum[ct];
      v += __shfl_xor(v, 16);
      v += __shfl_xor(v, 32);
      if (lane < 16) atomicAdd(&msum[colg[ct]], v);
    }
  }
  __syncthreads();   // B3
  {
    float* msH = half ? ms1 : ms0;
    if (t < 128) msH[(size_t)(b*128 + j)*128 + t] = msum[t];   // exclusive owner
  }

  // ---------- PASS U ----------
  floatx4 au[2][4];
  #pragma unroll
  for (int rt = 0; rt < 2; ++rt)
    #pragma unroll
    for (int ct = 0; ct < 4; ++ct) au[rt][ct] = (floatx4){0.f,0.f,0.f,0.f};
  #pragma unroll
  for (int kp = 0; kp < 2; ++kp) {
    uint4 bb[2][4];
    #pragma unroll
    for (int k2 = 0; k2 < 2; ++k2)
      #pragma unroll
      for (int ct = 0; ct < 4; ++ct)
        bb[k2][ct] = *(const uint4*)(wue + colg[ct]*64 + (kp*2 + k2)*16 + q*4);
    #pragma unroll
    for (int k2 = 0; k2 < 2; ++k2)
      #pragma unroll
      for (int rt = 0; rt < 2; ++rt)
        if (rt < nvt) {
          uint4 a = *(const uint4*)&e_s[arowi[rt]*68 + (kp*2 + k2)*16 + q*4];
          #pragma unroll
          for (int ct = 0; ct < 4; ++ct)
            au[rt][ct] = __builtin_amdgcn_mfma_f32_16x16x32_bf16(as_s8(a), as_s8(bb[k2][ct]), au[rt][ct], 0, 0, 0);
        }
  }
  #pragma unroll
  for (int kp = 0; kp < 2; ++kp) {
    uint4 bb[2][4];
    #pragma unroll
    for (int k2 = 0; k2 < 2; ++k2)
      #pragma unroll
      for (int ct = 0; ct < 4; ++ct)
        bb[k2][ct] = *(const uint4*)(wum + colg[ct]*64 + (kp*2 + k2)*16 + q*4);
    #pragma unroll
    for (int k2 = 0; k2 < 2; ++k2)
      #pragma unroll
      for (int rt = 0; rt < 2; ++rt)
        if (rt < nvt) {
          uint4 a = *(const uint4*)&m_a[arowi[rt]*68 + (kp*2 + k2)*16 + q*4];
          #pragma unroll
          for (int ct = 0; ct < 4; ++ct)
            au[rt][ct] = __builtin_amdgcn_mfma_f32_16x16x32_bf16(as_s8(a), as_s8(bb[k2][ct]), au[rt][ct], 0, 0, 0);
        }
  }
  __syncthreads();   // B4: all waves done reading m_a

  // U epilogue -> m16 (own 32-row x 64-col region), then per-wave writeback.
  // Same-wave LDS write->read: no barrier needed (B5 deleted).
  {
    float buv[4];
    #pragma unroll
    for (int ct = 0; ct < 4; ++ct) buv[ct] = bu_s[colg[ct]];
    #pragma unroll
    for (int rt = 0; rt < 2; ++rt)
      if (rt < nvt)
        #pragma unroll
        for (int ct = 0; ct < 4; ++ct)
          #pragma unroll
          for (int r = 0; r < 4; ++r) {
            int lrow = rh2*32 + rt*16 + q*4 + r;
            m16[lrow*136 + colg[ct]] = bf16_1(fmaxf(au[rt][ct][r] + buv[ct], 0.f));
          }
  }
  {
    const int c4 = ch*32 + (lane & 7) * 4;
    #pragma unroll
    for (int it = 0; it < 4; ++it) {
      int lr = rh2*32 + it*8 + (lane >> 3);
      if (row0 + lr < vn)
        *(uint4*)&eblk[(size_t)(row0 + lr)*64 + c4] = *(const uint4*)&m_a[lr*68 + c4];
    }
  }
}

// ---------- MFMA readout, both GEMMs on matrix cores ----------
__global__ __launch_bounds__(256,4) void readout_mfma(
  const unsigned* __restrict__ eg,
  const unsigned* __restrict__ wr1T,
  const unsigned* __restrict__ wr2T,
  const float* __restrict__ br1, const float* __restrict__ br2,
  const int* __restrict__ event_nums, float* __restrict__ out)
{
  __shared__ unsigned f_s[64*132];
  __shared__ int iu_s[64], ju_s[64];
  unsigned short* h16 = (unsigned short*)f_s;

  const int t = threadIdx.x;
  const int b = blockIdx.x / 127, pb = blockIdx.x % 127;
  const int vn = event_nums[b];

  if (t < 64) {
    int p = pb*64 + t;
    float disc = (float)((2*NN-1)*(2*NN-1) - 8*p);
    int iu = (int)(((float)(2*NN-1) - sqrtf(disc)) * 0.5f);
    if (iu < 0) iu = 0; if (iu > NN-2) iu = NN-2;
    while (iu < NN-2 && ((iu+1)*(2*NN-2-iu))/2 <= p) ++iu;
    while (iu > 0 && (iu*(2*NN-1-iu))/2 > p) --iu;
    int ju = p - (iu*(2*NN-1-iu))/2 + iu + 1;
    iu_s[t] = iu; ju_s[t] = ju;
  }
  __syncthreads();

  #pragma unroll
  for (int it = 0; it < 8; ++it) {
    int f4 = it*1024 + t*4;
    int pr = f4 >> 7, w = f4 & 127;
    int side = w >> 6, k2 = w & 63;
    int iu = iu_s[pr], ju = ju_s[pr];
    size_t base = side ? (((size_t)(b*128 + iu))*128 + ju)*64
                       : (((size_t)(b*128 + ju))*128 + iu)*64;
    *(uint4*)&f_s[pr*132 + w] = *(const uint4*)&eg[base + k2];
  }
  __syncthreads();

  const int lane = t & 63, wv = t >> 6;
  const int q = lane >> 4, n = lane & 15;
  int colg[4];
  #pragma unroll
  for (int ct = 0; ct < 4; ++ct) colg[ct] = wv*64 + ct*16 + n;

  floatx4 acc[4][4];
  #pragma unroll
  for (int rt = 0; rt < 4; ++rt)
    #pragma unroll
    for (int ct = 0; ct < 4; ++ct) acc[rt][ct] = (floatx4){0.f,0.f,0.f,0.f};

  #pragma unroll
  for (int kb = 0; kb < 8; ++kb) {
    uint4 bb[4];
    #pragma unroll
    for (int ct = 0; ct < 4; ++ct) bb[ct] = *(const uint4*)(wr1T + (size_t)colg[ct]*128 + kb*16 + q*4);
    #pragma unroll
    for (int rt = 0; rt < 4; ++rt) {
      uint4 a = *(const uint4*)&f_s[(rt*16 + n)*132 + kb*16 + q*4];
      #pragma unroll
      for (int ct = 0; ct < 4; ++ct)
        acc[rt][ct] = __builtin_amdgcn_mfma_f32_16x16x32_bf16(as_s8(a), as_s8(bb[ct]), acc[rt][ct], 0, 0, 0);
    }
  }
  __syncthreads();

  {
    float brv[4];
    #pragma unroll
    for (int ct = 0; ct < 4; ++ct) brv[ct] = br1[colg[ct]];
    #pragma unroll
    for (int rt = 0; rt < 4; ++rt)
      #pragma unroll
      for (int ct = 0; ct < 4; ++ct)
        #pragma unroll
        for (int r = 0; r < 4; ++r) {
          int pr = rt*16 + q*4 + r;
          h16[pr*264 + colg[ct]] = bf16_1(fmaxf(acc[rt][ct][r] + brv[ct], 0.f));
        }
  }
  __syncthreads();

  floatx4 acc2 = (floatx4){0.f,0.f,0.f,0.f};
  #pragma unroll
  for (int kb = 0; kb < 8; ++kb) {
    uint4 bb = *(const uint4*)(wr2T + n*128 + kb*16 + q*4);
    uint4 a  = *(const uint4*)&f_s[(wv*16 + n)*132 + kb*16 + q*4];
    acc2 = __builtin_amdgcn_mfma_f32_16x16x32_bf16(as_s8(a), as_s8(bb), acc2, 0, 0, 0);
  }

  if (n < 10) {
    float bias = br2[n];
    #pragma unroll
    for (int r = 0; r < 4; ++r) {
      int pr = wv*16 + q*4 + r;
      int iu = iu_s[pr], ju = ju_s[pr];
      if (ju < vn) {
        int idx = iu*vn - (iu*(iu+1))/2 + (ju - iu - 1);
        out[(((size_t)b*5 + (n>>1))*PP + idx)*2 + (n&1)] = acc2[r] + bias;
      }
    }
  }
}

extern "C" void kernel_launch(void* const* d_in, const int* in_sizes, int n_in,
                              void* d_out, int out_size, void* d_ws, size_t ws_size,
                              hipStream_t stream) {
  const int*   edge_ids      = (const int*)d_in[0];
  const float* node_features = (const float*)d_in[1];
  const int*   event_nums    = (const int*)d_in[3];
  const float* emb  = (const float*)d_in[4];
  const float* Wl_e = (const float*)d_in[5];
  const float* Wl_w = (const float*)d_in[6];
  const float* Wl_v = (const float*)d_in[7];
  const float* bl1  = (const float*)d_in[8];
  const float* wl2  = (const float*)d_in[9];
  const float* bl2  = (const float*)d_in[10];
  const float* Wm_w = (const float*)d_in[11];
  const float* Wm_v = (const float*)d_in[12];
  const float* Wm_e = (const float*)d_in[13];
  const float* bm   = (const float*)d_in[14];
  const float* Wu_e = (const float*)d_in[15];
  const float* Wu_m = (const float*)d_in[16];
  const float* bu   = (const float*)d_in[17];
  const float* W_ih = (const float*)d_in[18];
  const float* W_hh = (const float*)d_in[19];
  const float* b_ih = (const float*)d_in[20];
  const float* b_hh = (const float*)d_in[21];
  const float* Wr1  = (const float*)d_in[22];
  const float* br1  = (const float*)d_in[23];
  const float* Wr2  = (const float*)d_in[24];
  const float* br2  = (const float*)d_in[25];

  const size_t SZ_E = (size_t)134217728;       // B*N*N*64 u32
  const size_t SZ_S = (size_t)2097152;         // B*N*128 f32
  const size_t SZ_W = (size_t)131072;          // 32768 u32
  const size_t SZ_W2 = (size_t)8192;           // 2048 u32
  const size_t SZ_TAB = (size_t)2048;          // 512 f32 each
  const size_t SZ_WIH = (size_t)98304;         // 24576 u32 (384 cols x 64)
  const size_t SZ_W4  = (size_t)131072;        // 32768 u32 (512 cols x 64)
  const size_t need = SZ_E + 7*SZ_S + 2*SZ_W + SZ_W2 + 3*SZ_TAB + 2*SZ_WIH + SZ_W4;

  hipMemsetAsync(d_out, 0, (size_t)out_size * sizeof(float), stream);
  if (ws_size < need) return;

  char* w = (char*)d_ws;
  unsigned* eg   = (unsigned*)w; w += SZ_E;
  float* h_ws = (float*)w; w += SZ_S;
  float* a_l  = (float*)w; w += SZ_S;
  float* b_l  = (float*)w; w += SZ_S;
  float* a_m  = (float*)w; w += SZ_S;
  float* b_m  = (float*)w; w += SZ_S;
  float* ms0  = (float*)w; w += SZ_S;
  float* ms1  = (float*)w; w += SZ_S;
  unsigned* wT   = (unsigned*)w; w += SZ_W;
  unsigned* wr1T = (unsigned*)w; w += SZ_W;
  unsigned* wr2T = (unsigned*)w; w += SZ_W2;
  float* embZ = (float*)w; w += SZ_TAB;
  float* embM = (float*)w; w += SZ_TAB;
  float* embU = (float*)w; w += SZ_TAB;
  unsigned* wihT = (unsigned*)w; w += SZ_WIH;
  unsigned* whhT = (unsigned*)w; w += SZ_WIH;
  unsigned* w4T  = (unsigned*)w; w += SZ_W4;

  hipLaunchKernelGGL(conv_w_kernel, dim3(576), dim3(256), 0, stream,
      Wl_e, Wm_e, Wu_e, Wu_m, Wr1, Wr2, emb,
      W_ih, W_hh, Wl_w, Wl_v, Wm_w, Wm_v,
      wT, wr1T, wr2T, embZ, embM, embU, wihT, whhT, w4T);

  hipLaunchKernelGGL(gru_mfma, dim3(256), dim3(256), 0, stream,
      0, ms0, ms1, node_features, h_ws, wihT, whhT, w4T,
      b_ih, b_hh, event_nums, a_l, b_l, a_m, b_m);

  for (int r = 0; r < 3; ++r) {
    if (r == 0) {
      hipLaunchKernelGGL(edge_round_first, dim3(8192), dim3(256), 0, stream,
          eg, wT, edge_ids, embZ, embM, embU,
          a_l, b_l, a_m, b_m, bl1, wl2, bl2, bm, bu, event_nums, ms0, ms1);
    } else {
      hipLaunchKernelGGL(edge_round_rest, dim3(8192), dim3(256), 0, stream,
          eg, wT, a_l, b_l, a_m, b_m, bl1, wl2, bl2, bm, bu, event_nums, ms0, ms1);
    }
    if (r < 2) {
      const float* hin = (r == 0) ? node_features : h_ws;
      hipLaunchKernelGGL(gru_mfma, dim3(256), dim3(256), 0, stream,
          1, ms0, ms1, hin, h_ws, wihT, whhT, w4T,
          b_ih, b_hh, event_nums, a_l, b_l, a_m, b_m);
    }
  }

  hipLaunchKernelGGL(readout_mfma, dim3(BB*127), dim3(256), 0, stream,
      eg, wr1T, wr2T, br1, br2, event_nums, (float*)d_out);
}